// Round 13
// baseline (682.487 us; speedup 1.0000x reference)
//
#include <hip/hip_runtime.h>
#include <math.h>

#define T_LEN 215
#define TP    224   // padded T (14 * 16)
#define B_N   128
#define DINP  36
#define D_TR  160
#define HD    40
#define D_FIN 196
#define KPG   864   // 860 padded to mult of 32

typedef __attribute__((ext_vector_type(8))) short short8v;
typedef __attribute__((ext_vector_type(4))) float f32x4;

__device__ __forceinline__ ushort f2bf(float x) {
  union { float f; unsigned u; } c; c.f = x;
  unsigned r = c.u + 0x7fffu + ((c.u >> 16) & 1u);
  return (ushort)(r >> 16);
}
__device__ __forceinline__ float bf2f(ushort h) {
  union { unsigned u; float f; } c; c.u = ((unsigned)h) << 16;
  return c.f;
}

// ---------------- mega-prep: weight converts + zeros + emb + xb16 ----------------
// flat blocks [0,7770): conversions/zeros/emb/obuf-pad; blocks [7770,7898): xb16 per b.
__global__ __launch_bounds__(256) void k_prep(const float* __restrict__ Wv1,
    const float* __restrict__ Wv2, const float* __restrict__ ipw, const float* __restrict__ ow,
    const float* __restrict__ l1w, const float* __restrict__ l2w,
    const float* __restrict__ src, const float* __restrict__ R_u,
    const float* __restrict__ stat, const float* __restrict__ emb_w, const float* __restrict__ emb_b,
    ushort* __restrict__ wv1b, ushort* __restrict__ wv2b, ushort* __restrict__ ipwb,
    ushort* __restrict__ owb, ushort* __restrict__ l1wb, ushort* __restrict__ l2wb,
    float* __restrict__ featacc, ushort* __restrict__ obuf16, ushort* __restrict__ xb16) {
  __shared__ float Ss[T_LEN * DINP];
  if (blockIdx.x >= 7770) {   // ---- xb16 path (one block per b) ----
    const int b = blockIdx.x - 7770, tid = threadIdx.x;
    for (int i = tid; i < T_LEN * DINP; i += 256) {
      int t = i / DINP, j = i - t * DINP;
      Ss[i] = src[((size_t)t * B_N + b) * 72 + j];
    }
    __syncthreads();
    for (int i = tid; i < DINP * T_LEN; i += 256) {
      int ii = i / T_LEN, t = i - ii * T_LEN;
      float v = Ss[t * DINP + ii];
      float4 r = ((const float4*)R_u)[ii];
      ushort4 o;
      o.x = f2bf(fmaxf(v * r.x, 0.f)); o.y = f2bf(fmaxf(v * r.y, 0.f));
      o.z = f2bf(fmaxf(v * r.z, 0.f)); o.w = f2bf(fmaxf(v * r.w, 0.f));
      ushort* row = xb16 + (size_t)(b * DINP + ii) * KPG;
      *(ushort4*)(row + 4 * t) = o;
      if (t == 0) { ushort4 z = {0, 0, 0, 0}; *(ushort4*)(row + 860) = z; }
    }
    return;
  }
  int i = blockIdx.x * 256 + threadIdx.x;
  if (i < 746496) { int n = i / KPG, k = i % KPG;
    wv1b[i] = (n < 860 && k < 860) ? f2bf(Wv1[n * 860 + k]) : (ushort)0; return; }
  i -= 746496;
  if (i < 746496) { int n = i / KPG, k = i % KPG;
    wv2b[i] = (n < 860 && k < 860) ? f2bf(Wv2[n * 860 + k]) : (ushort)0; return; }
  i -= 746496;
  if (i < 153600) { ipwb[i] = f2bf(ipw[i]); return; }
  i -= 153600;
  if (i < 51200)  { owb[i] = f2bf(ow[i]); return; }
  i -= 51200;
  if (i < 40960)  { l1wb[i] = f2bf(l1w[i]); return; }
  i -= 40960;
  if (i < 40960)  { l2wb[i] = f2bf(l2w[i]); return; }
  i -= 40960;
  if (i < 20480)  { int b = i / D_TR, d = i - b * D_TR;   // zero featacc cols < 160
    featacc[b * D_FIN + d] = 0.f; return; }
  i -= 20480;
  if (i < 4608)   { int b = i / DINP, ii = i - b * DINP;  // emb -> featacc cols 160..195
    float s = emb_b[ii];
    #pragma unroll
    for (int k = 0; k < 9; k++) s = fmaf(stat[b * 9 + k], emb_w[ii * 9 + k], s);
    featacc[b * D_FIN + D_TR + ii] = s; return; }
  i -= 4608;
  if (i < 184320) {  // zero obuf16 pad rows t in [215,224)
    int b = i / 1440, rem = i % 1440;
    int t = 215 + rem / 160, cc = rem % 160;
    obuf16[((size_t)b * TP + t) * D_TR + cc] = 0; return;
  }
}

// ---------------- fused graph tail (one block per b): s1 reduce -> matvec Wv2 -> buildx ----------------
__global__ __launch_bounds__(256) void k_graphtail(const ushort* __restrict__ V1b,
    const ushort* __restrict__ wv2b, const float* __restrict__ bv2,
    const float* __restrict__ times, ushort* __restrict__ x16) {
  __shared__ ushort s1l[KPG];
  __shared__ float  v2l[KPG];
  const int b = blockIdx.x, tid = threadIdx.x;
  const int wave = tid >> 6, lane = tid & 63;

  // step 1: s1[n] = (1/36) sum_i V1b[b*36+i, n]  (lanes coalesced over n)
  for (int n = tid; n < KPG; n += 256) {
    float s = 0.f;
    if (n < 860) {
      #pragma unroll 4
      for (int i = 0; i < DINP; i++) s += bf2f(V1b[((size_t)(b * DINP + i)) * 860 + n]);
      s *= (1.0f / 36.0f);
    }
    s1l[n] = f2bf(s);
  }
  __syncthreads();

  // step 2: v2[n] = s1 . Wv2[n,:]  — wave per 216 outputs, lanes split K (coalesced),
  // 2 outputs interleaved to break the FMA dependence chain.
  {
    const int nbase = wave * 216;
    for (int nn = 0; nn < 216; nn += 2) {
      const int n0 = nbase + nn, n1 = n0 + 1;
      const ushort* w0 = wv2b + (size_t)n0 * KPG;
      const ushort* w1 = wv2b + (size_t)n1 * KPG;
      float a0 = 0.f, a1 = 0.f;
      for (int k = lane; k < KPG; k += 64) {
        float sv = bf2f(s1l[k]);
        a0 = fmaf(sv, bf2f(w0[k]), a0);
        a1 = fmaf(sv, bf2f(w1[k]), a1);
      }
      #pragma unroll
      for (int off = 32; off; off >>= 1) {
        a0 += __shfl_xor(a0, off, 64);
        a1 += __shfl_xor(a1, off, 64);
      }
      if (lane == 0) { v2l[n0] = a0; v2l[n1] = a1; }
    }
  }
  __syncthreads();

  // step 3: x16[b, t, *] = [relu(v2[4t..4t+3]+bv2) replicated over c<36 | pe(t,b)]
  for (int idx = tid; idx < TP * 40; idx += 256) {
    int c = idx % 40, t = idx / 40;
    float4 f = {0.f, 0.f, 0.f, 0.f};
    if (t < T_LEN) {
      if (c < 36) {
        float4 bb = *(const float4*)&bv2[4 * t];
        f.x = fmaxf(v2l[4 * t]     + bb.x, 0.f);
        f.y = fmaxf(v2l[4 * t + 1] + bb.y, 0.f);
        f.z = fmaxf(v2l[4 * t + 2] + bb.z, 0.f);
        f.w = fmaxf(v2l[4 * t + 3] + bb.w, 0.f);
      } else {
        float tm = times[t * B_N + b];
        int j0 = (c - 36) * 4;
        bool is_sin = j0 < 8;
        int kb = j0 & 7;
        float o[4];
        #pragma unroll
        for (int qq = 0; qq < 4; qq++) {
          float ts = expf((float)(kb + qq) * 0.76723400f);  // 215^(k/7)
          float sc = tm / ts;
          o[qq] = is_sin ? sinf(sc) : cosf(sc);
        }
        f.x = o[0]; f.y = o[1]; f.z = o[2]; f.w = o[3];
      }
    }
    ushort4 h = {f2bf(f.x), f2bf(f.y), f2bf(f.z), f2bf(f.w)};
    *(ushort4*)(x16 + ((size_t)b * TP + t) * D_TR + 4 * c) = h;
  }
}

// ---------------- bf16 MFMA GEMM: C = act(A[M,KP] @ W[N,KP]^T + bias), BN templated ----------------
template <int RELU, int WMODE, int BNT>
__global__ __launch_bounds__(256) void gemm_bf16(const ushort* __restrict__ A,
    const ushort* __restrict__ W, const float* __restrict__ bias, void* __restrict__ Cv,
    int KP, int ldc, int ncols, int kts) {
  __shared__ ushort As[128 * 32];
  __shared__ ushort Ws[BNT * 32];
  constexpr int NJ = BNT / 16;
  const int tid = threadIdx.x;
  const int wave = tid >> 6, lane = tid & 63;
  const int lr = lane & 15, hi = lane >> 4;
  const int m0 = blockIdx.y * 128, n0 = blockIdx.x * BNT;

  f32x4 acc[2][NJ];
  #pragma unroll
  for (int i = 0; i < 2; i++)
    #pragma unroll
    for (int j = 0; j < NJ; j++) acc[i][j] = (f32x4){0.f, 0.f, 0.f, 0.f};

  const int ar = tid >> 2, g = tid & 3;
  const size_t abase0 = (size_t)(m0 + ar) * KP;
  const size_t abase1 = (size_t)(m0 + ar + 64) * KP;
  const size_t bbase0 = (size_t)(n0 + ar) * KP;
  const size_t bbase1 = (size_t)(n0 + ar + 64) * KP;
  const int awb0 = ar * 64 + ((g * 16) ^ ((ar & 3) << 4));
  const int awb1 = awb0 + 64 * 64;

  const int arow0 = wave * 32 + lr;
  const int arb0 = arow0 * 64 + ((hi * 16) ^ ((arow0 & 3) << 4));
  const int arb1 = (arow0 + 16) * 64 + ((hi * 16) ^ (((arow0 + 16) & 3) << 4));
  int brb[NJ];
  #pragma unroll
  for (int j = 0; j < NJ; j++)
    brb[j] = (j * 16 + lr) * 64 + ((hi * 16) ^ ((lr & 3) << 4));

  for (int kt = 0; kt < kts; ++kt) {
    const int k0 = kt * 32;
    uint4 va0 = *(const uint4*)(A + abase0 + k0 + g * 8);
    uint4 va1 = *(const uint4*)(A + abase1 + k0 + g * 8);
    uint4 vb0 = *(const uint4*)(W + bbase0 + k0 + g * 8);
    uint4 vb1;
    if constexpr (BNT == 128) vb1 = *(const uint4*)(W + bbase1 + k0 + g * 8);
    if (kt) __syncthreads();
    *(uint4*)((char*)As + awb0) = va0;
    *(uint4*)((char*)As + awb1) = va1;
    *(uint4*)((char*)Ws + awb0) = vb0;
    if constexpr (BNT == 128) *(uint4*)((char*)Ws + awb1) = vb1;
    __syncthreads();
    short8v a0 = *(const short8v*)((const char*)As + arb0);
    short8v a1 = *(const short8v*)((const char*)As + arb1);
    #pragma unroll
    for (int j = 0; j < NJ; j++) {
      short8v bf = *(const short8v*)((const char*)Ws + brb[j]);
      acc[0][j] = __builtin_amdgcn_mfma_f32_16x16x32_bf16(a0, bf, acc[0][j], 0, 0, 0);
      acc[1][j] = __builtin_amdgcn_mfma_f32_16x16x32_bf16(a1, bf, acc[1][j], 0, 0, 0);
    }
  }

  #pragma unroll
  for (int i = 0; i < 2; i++) {
    #pragma unroll
    for (int j = 0; j < NJ; j++) {
      int col = n0 + j * 16 + lr;
      int row = m0 + wave * 32 + i * 16 + hi * 4;
      if (col < ncols) {
        float bb = bias ? bias[col] : 0.f;
        #pragma unroll
        for (int r = 0; r < 4; r++) {
          float xv = acc[i][j][r] + bb;
          if (RELU) xv = fmaxf(xv, 0.f);
          if (WMODE == 0) ((float*)Cv)[(size_t)(row + r) * ldc + col] = xv;
          else            ((ushort*)Cv)[(size_t)(row + r) * ldc + col] = f2bf(xv);
        }
      }
    }
  }
}

// ---------------- qkv GEMM (BN=128): writes Q,K to qkvB[b-major][480]; V transposed to Vt ----------------
__global__ __launch_bounds__(256) void gemm_qkv(const ushort* __restrict__ A,
    const ushort* __restrict__ W, const float* __restrict__ bias,
    ushort* __restrict__ qkvB, ushort* __restrict__ Vt, int kts) {
  __shared__ ushort As[128 * 32];
  __shared__ ushort Ws[128 * 32];
  const int KP = 160;
  const int tid = threadIdx.x;
  const int wave = tid >> 6, lane = tid & 63;
  const int lr = lane & 15, hi = lane >> 4;
  const int m0 = blockIdx.y * 128, n0 = blockIdx.x * 128;

  f32x4 acc[2][8];
  #pragma unroll
  for (int i = 0; i < 2; i++)
    #pragma unroll
    for (int j = 0; j < 8; j++) acc[i][j] = (f32x4){0.f, 0.f, 0.f, 0.f};

  const int ar = tid >> 2, g = tid & 3;
  const size_t abase0 = (size_t)(m0 + ar) * KP;
  const size_t abase1 = (size_t)(m0 + ar + 64) * KP;
  const size_t bbase0 = (size_t)(n0 + ar) * KP;
  const size_t bbase1 = (size_t)(n0 + ar + 64) * KP;
  const int awb0 = ar * 64 + ((g * 16) ^ ((ar & 3) << 4));
  const int awb1 = awb0 + 64 * 64;

  const int arow0 = wave * 32 + lr;
  const int arb0 = arow0 * 64 + ((hi * 16) ^ ((arow0 & 3) << 4));
  const int arb1 = (arow0 + 16) * 64 + ((hi * 16) ^ (((arow0 + 16) & 3) << 4));
  int brb[8];
  #pragma unroll
  for (int j = 0; j < 8; j++)
    brb[j] = (j * 16 + lr) * 64 + ((hi * 16) ^ ((lr & 3) << 4));

  for (int kt = 0; kt < kts; ++kt) {
    const int k0 = kt * 32;
    uint4 va0 = *(const uint4*)(A + abase0 + k0 + g * 8);
    uint4 va1 = *(const uint4*)(A + abase1 + k0 + g * 8);
    uint4 vb0 = *(const uint4*)(W + bbase0 + k0 + g * 8);
    uint4 vb1 = *(const uint4*)(W + bbase1 + k0 + g * 8);
    if (kt) __syncthreads();
    *(uint4*)((char*)As + awb0) = va0;
    *(uint4*)((char*)As + awb1) = va1;
    *(uint4*)((char*)Ws + awb0) = vb0;
    *(uint4*)((char*)Ws + awb1) = vb1;
    __syncthreads();
    short8v a0 = *(const short8v*)((const char*)As + arb0);
    short8v a1 = *(const short8v*)((const char*)As + arb1);
    #pragma unroll
    for (int j = 0; j < 8; j++) {
      short8v bf = *(const short8v*)((const char*)Ws + brb[j]);
      acc[0][j] = __builtin_amdgcn_mfma_f32_16x16x32_bf16(a0, bf, acc[0][j], 0, 0, 0);
      acc[1][j] = __builtin_amdgcn_mfma_f32_16x16x32_bf16(a1, bf, acc[1][j], 0, 0, 0);
    }
  }

  #pragma unroll
  for (int i = 0; i < 2; i++) {
    const int row = m0 + wave * 32 + i * 16 + hi * 4;   // = b*224 + t0 (4 consecutive t)
    const int b = row / TP, t0 = row - b * TP;
    #pragma unroll
    for (int j = 0; j < 8; j++) {
      int col = n0 + j * 16 + lr;
      if (col < 320) {               // Q or K
        float bb = bias[col];
        #pragma unroll
        for (int r = 0; r < 4; r++)
          qkvB[(size_t)(row + r) * 480 + col] = f2bf(acc[i][j][r] + bb);
      } else if (col < 480) {        // V: transposed packed store
        float bb = bias[col];
        int dg = col - 320;
        int hh = dg / 40, dd = dg - hh * 40;
        ushort4 pv;
        pv.x = f2bf(acc[i][j][0] + bb); pv.y = f2bf(acc[i][j][1] + bb);
        pv.z = f2bf(acc[i][j][2] + bb); pv.w = f2bf(acc[i][j][3] + bb);
        *(ushort4*)(Vt + (((size_t)(b * 4 + hh) * 48 + dd) * TP + t0)) = pv;
      }
    }
  }
}

// ---------------- fused layer tail: [attn-out GEMM + res + LN1] -> [FF1] -> [FF2 + res + LN2] ----------------
__global__ __launch_bounds__(256) void gemm_lnff(const ushort* __restrict__ Ao,
    const ushort* __restrict__ Wo, const float* __restrict__ bo,
    const float* __restrict__ g1, const float* __restrict__ be1,
    const ushort* __restrict__ W1, const float* __restrict__ b1,
    const ushort* __restrict__ W2, const float* __restrict__ b2,
    const float* __restrict__ g2, const float* __restrict__ be2,
    ushort* __restrict__ x16, const int* __restrict__ lengths,
    float* __restrict__ featacc) {
  __shared__ ushort As[64 * 32];
  __shared__ ushort Ws[160 * 32];
  __shared__ ushort W1s[128 * 32];
  __shared__ ushort W2s[160 * 32];
  __shared__ ushort Xln[64 * 168];
  __shared__ ushort Hs[64 * 136];
  const int tid = threadIdx.x;
  const int wave = tid >> 6, lane = tid & 63;
  const int lr = lane & 15, hi = lane >> 4;
  const int m0 = blockIdx.x * 64;

  const int ar = tid >> 2, g = tid & 3;
  const int awb = ar * 64 + ((g * 16) ^ ((ar & 3) << 4));
  const int awb1 = awb + 64 * 64;
  const int wr0 = tid >> 2,         ws0 = tid & 3;
  const int wr1 = (tid + 256) >> 2, ws1 = (tid + 256) & 3;
  const int wr2 = (tid + 512) >> 2, ws2 = (tid + 512) & 3;
  const int wwb0 = wr0 * 64 + ((ws0 * 16) ^ ((wr0 & 3) << 4));
  const int wwb1 = wr1 * 64 + ((ws1 * 16) ^ ((wr1 & 3) << 4));
  const int wwb2 = wr2 * 64 + ((ws2 * 16) ^ ((wr2 & 3) << 4));
  const int arow = wave * 16 + lr;
  const int arb = arow * 64 + ((hi * 16) ^ ((arow & 3) << 4));
  int brb[10];
  #pragma unroll
  for (int j = 0; j < 10; j++)
    brb[j] = (j * 16 + lr) * 64 + ((hi * 16) ^ ((lr & 3) << 4));

  const int lrow0 = wave * 16 + hi * 4;
  const int rb = m0 + lrow0;

  // ======== phase A: attn-out GEMM (K=160) + bias + residual + LN1 -> Xln ========
  {
    f32x4 acc[10];
    #pragma unroll
    for (int j = 0; j < 10; j++) acc[j] = (f32x4){0.f, 0.f, 0.f, 0.f};
    const size_t abase = (size_t)(m0 + ar) * 160;
    for (int kt = 0; kt < 5; ++kt) {
      const int k0 = kt * 32;
      uint4 va = *(const uint4*)(Ao + abase + k0 + g * 8);
      uint4 w0 = *(const uint4*)(Wo + (size_t)wr0 * 160 + k0 + ws0 * 8);
      uint4 w1 = *(const uint4*)(Wo + (size_t)wr1 * 160 + k0 + ws1 * 8);
      uint4 w2;
      if (tid < 128) w2 = *(const uint4*)(Wo + (size_t)wr2 * 160 + k0 + ws2 * 8);
      if (kt) __syncthreads();
      *(uint4*)((char*)As + awb) = va;
      *(uint4*)((char*)Ws + wwb0) = w0;
      *(uint4*)((char*)Ws + wwb1) = w1;
      if (tid < 128) *(uint4*)((char*)Ws + wwb2) = w2;
      __syncthreads();
      short8v a0 = *(const short8v*)((const char*)As + arb);
      #pragma unroll
      for (int j = 0; j < 10; j++) {
        short8v bf = *(const short8v*)((const char*)Ws + brb[j]);
        acc[j] = __builtin_amdgcn_mfma_f32_16x16x32_bf16(a0, bf, acc[j], 0, 0, 0);
      }
    }
    float s[4] = {0.f, 0.f, 0.f, 0.f};
    #pragma unroll
    for (int j = 0; j < 10; j++) {
      const int col = j * 16 + lr;
      const float bb = bo[col];
      #pragma unroll
      for (int r = 0; r < 4; r++) {
        float v = acc[j][r] + bb + bf2f(x16[(size_t)(rb + r) * D_TR + col]);
        acc[j][r] = v;
        s[r] += v;
      }
    }
    #pragma unroll
    for (int r = 0; r < 4; r++) {
      s[r] += __shfl_xor(s[r], 1, 64);
      s[r] += __shfl_xor(s[r], 2, 64);
      s[r] += __shfl_xor(s[r], 4, 64);
      s[r] += __shfl_xor(s[r], 8, 64);
    }
    float mu[4], q2[4] = {0.f, 0.f, 0.f, 0.f};
    #pragma unroll
    for (int r = 0; r < 4; r++) mu[r] = s[r] * (1.0f / 160.0f);
    #pragma unroll
    for (int j = 0; j < 10; j++)
      #pragma unroll
      for (int r = 0; r < 4; r++) {
        float d = acc[j][r] - mu[r];
        q2[r] += d * d;
      }
    #pragma unroll
    for (int r = 0; r < 4; r++) {
      q2[r] += __shfl_xor(q2[r], 1, 64);
      q2[r] += __shfl_xor(q2[r], 2, 64);
      q2[r] += __shfl_xor(q2[r], 4, 64);
      q2[r] += __shfl_xor(q2[r], 8, 64);
    }
    float rstd[4];
    #pragma unroll
    for (int r = 0; r < 4; r++) rstd[r] = rsqrtf(q2[r] * (1.0f / 160.0f) + 1e-5f);
    #pragma unroll
    for (int j = 0; j < 10; j++) {
      const int col = j * 16 + lr;
      const float gc = g1[col], bc = be1[col];
      #pragma unroll
      for (int r = 0; r < 4; r++) {
        float o = (acc[j][r] - mu[r]) * rstd[r] * gc + bc;
        Xln[(lrow0 + r) * 168 + col] = f2bf(o);
      }
    }
  }
  __syncthreads();

  // ======== phase B: h = relu(Xln @ W1^T + b1) -> Hs ========
  {
    f32x4 acc1[8];
    #pragma unroll
    for (int j = 0; j < 8; j++) acc1[j] = (f32x4){0.f, 0.f, 0.f, 0.f};
    int brb8[8];
    #pragma unroll
    for (int j = 0; j < 8; j++)
      brb8[j] = (j * 16 + lr) * 64 + ((hi * 16) ^ ((lr & 3) << 4));
    for (int kt = 0; kt < 5; ++kt) {
      const int k0 = kt * 32;
      uint4 w10 = *(const uint4*)(W1 + (size_t)ar * 160 + k0 + g * 8);
      uint4 w11 = *(const uint4*)(W1 + (size_t)(ar + 64) * 160 + k0 + g * 8);
      if (kt) __syncthreads();
      *(uint4*)((char*)W1s + awb) = w10;
      *(uint4*)((char*)W1s + awb1) = w11;
      __syncthreads();
      short8v a0 = *(const short8v*)(&Xln[(wave * 16 + lr) * 168 + k0 + hi * 8]);
      #pragma unroll
      for (int j = 0; j < 8; j++) {
        short8v bf = *(const short8v*)((const char*)W1s + brb8[j]);
        acc1[j] = __builtin_amdgcn_mfma_f32_16x16x32_bf16(a0, bf, acc1[j], 0, 0, 0);
      }
    }
    #pragma unroll
    for (int j = 0; j < 8; j++) {
      const int col = j * 16 + lr;
      const float bb = b1[col];
      #pragma unroll
      for (int r = 0; r < 4; r++)
        Hs[(lrow0 + r) * 136 + col] = f2bf(fmaxf(acc1[j][r] + bb, 0.f));
    }
  }
  __syncthreads();

  // ======== phase C: o = Hs @ W2^T + b2; + Xln residual + LN2 -> x16 / featacc ========
  {
    f32x4 acc[10];
    #pragma unroll
    for (int j = 0; j < 10; j++) acc[j] = (f32x4){0.f, 0.f, 0.f, 0.f};
    for (int kt = 0; kt < 4; ++kt) {
      const int k0 = kt * 32;
      uint4 w0 = *(const uint4*)(W2 + (size_t)wr0 * 128 + k0 + ws0 * 8);
      uint4 w1 = *(const uint4*)(W2 + (size_t)wr1 * 128 + k0 + ws1 * 8);
      uint4 w2;
      if (tid < 128) w2 = *(const uint4*)(W2 + (size_t)wr2 * 128 + k0 + ws2 * 8);
      if (kt) __syncthreads();
      *(uint4*)((char*)W2s + wwb0) = w0;
      *(uint4*)((char*)W2s + wwb1) = w1;
      if (tid < 128) *(uint4*)((char*)W2s + wwb2) = w2;
      __syncthreads();
      short8v a0 = *(const short8v*)(&Hs[(wave * 16 + lr) * 136 + k0 + hi * 8]);
      #pragma unroll
      for (int j = 0; j < 10; j++) {
        short8v bf = *(const short8v*)((const char*)W2s + brb[j]);
        acc[j] = __builtin_amdgcn_mfma_f32_16x16x32_bf16(a0, bf, acc[j], 0, 0, 0);
      }
    }
    float s[4] = {0.f, 0.f, 0.f, 0.f};
    #pragma unroll
    for (int j = 0; j < 10; j++) {
      const int col = j * 16 + lr;
      const float bb = b2[col];
      #pragma unroll
      for (int r = 0; r < 4; r++) {
        float v = acc[j][r] + bb + bf2f(Xln[(lrow0 + r) * 168 + col]);
        acc[j][r] = v;
        s[r] += v;
      }
    }
    #pragma unroll
    for (int r = 0; r < 4; r++) {
      s[r] += __shfl_xor(s[r], 1, 64);
      s[r] += __shfl_xor(s[r], 2, 64);
      s[r] += __shfl_xor(s[r], 4, 64);
      s[r] += __shfl_xor(s[r], 8, 64);
    }
    float mu[4], q2[4] = {0.f, 0.f, 0.f, 0.f};
    #pragma unroll
    for (int r = 0; r < 4; r++) mu[r] = s[r] * (1.0f / 160.0f);
    #pragma unroll
    for (int j = 0; j < 10; j++)
      #pragma unroll
      for (int r = 0; r < 4; r++) {
        float d = acc[j][r] - mu[r];
        q2[r] += d * d;
      }
    #pragma unroll
    for (int r = 0; r < 4; r++) {
      q2[r] += __shfl_xor(q2[r], 1, 64);
      q2[r] += __shfl_xor(q2[r], 2, 64);
      q2[r] += __shfl_xor(q2[r], 4, 64);
      q2[r] += __shfl_xor(q2[r], 8, 64);
    }
    float rstd[4];
    #pragma unroll
    for (int r = 0; r < 4; r++) rstd[r] = rsqrtf(q2[r] * (1.0f / 160.0f) + 1e-5f);

    if (featacc == nullptr) {
      #pragma unroll
      for (int j = 0; j < 10; j++) {
        const int col = j * 16 + lr;
        const float gc = g2[col], bc = be2[col];
        #pragma unroll
        for (int r = 0; r < 4; r++) {
          float o = (acc[j][r] - mu[r]) * rstd[r] * gc + bc;
          x16[(size_t)(rb + r) * D_TR + col] = f2bf(o);
        }
      }
    } else {
      const int b = rb / TP, t0 = rb - b * TP;
      int L = lengths[b]; if (L > T_LEN) L = T_LEN;
      #pragma unroll
      for (int j = 0; j < 10; j++) {
        const int col = j * 16 + lr;
        const float gc = g2[col], bc = be2[col];
        float sacc = 0.f;
        #pragma unroll
        for (int r = 0; r < 4; r++) {
          float o = (acc[j][r] - mu[r]) * rstd[r] * gc + bc;
          if (t0 + r < L) sacc += o;
        }
        if (t0 < L) atomicAdd(&featacc[b * D_FIN + col], sacc);
      }
    }
  }
}

// ---------------- barrier-free 1-wave flash attention (b-major qkv + Vt) ----------------
__global__ __launch_bounds__(64) void k_attn4(const ushort* __restrict__ qkvB,
    const ushort* __restrict__ Vt, const int* __restrict__ lengths,
    ushort* __restrict__ o16) {
  __shared__ ushort SP[16 * 232];
  const int bh = blockIdx.x;
  const int b = bh >> 2, h = bh & 3;
  int L = lengths[b]; if (L > T_LEN) L = T_LEN;
  const int q0 = blockIdx.y << 4;
  if (q0 >= L) return;
  const int lane = threadIdx.x;
  const int lr = lane & 15, hi = lane >> 4;
  const int nk16 = (L + 15) >> 4;
  const int nkt  = (L + 31) >> 5;
  const float SC = 0.15811388300841898f;  // 1/sqrt(40)

  const ushort* qrow = qkvB + ((size_t)b * TP + q0) * 480 + h * 40;
  uint4 qa0u = *(const uint4*)(qrow + lr * 480 + hi * 8);
  uint4 qa1u = {0, 0, 0, 0};
  if (hi == 0) qa1u = *(const uint4*)(qrow + lr * 480 + 32);
  short8v qa0 = *(short8v*)&qa0u;
  short8v qa1 = *(short8v*)&qa1u;

  f32x4 c[14];
  #pragma unroll
  for (int kt = 0; kt < 14; ++kt) {
    c[kt] = (f32x4){0.f, 0.f, 0.f, 0.f};
    if (kt < nk16) {
      const ushort* krow = qkvB + ((size_t)b * TP + kt * 16) * 480 + 160 + h * 40;
      uint4 kb0u = *(const uint4*)(krow + lr * 480 + hi * 8);
      uint4 kb1u = {0, 0, 0, 0};
      if (hi == 0) kb1u = *(const uint4*)(krow + lr * 480 + 32);
      c[kt] = __builtin_amdgcn_mfma_f32_16x16x32_bf16(qa0, *(short8v*)&kb0u, c[kt], 0, 0, 0);
      c[kt] = __builtin_amdgcn_mfma_f32_16x16x32_bf16(qa1, *(short8v*)&kb1u, c[kt], 0, 0, 0);
    }
  }

  float mx[4] = {-1e30f, -1e30f, -1e30f, -1e30f};
  #pragma unroll
  for (int kt = 0; kt < 14; ++kt) {
    if (kt < nk16) {
      bool valid = (kt * 16 + lr) < L;
      #pragma unroll
      for (int r = 0; r < 4; r++) {
        float v = valid ? c[kt][r] : -1e30f;
        mx[r] = fmaxf(mx[r], v);
      }
    }
  }
  #pragma unroll
  for (int r = 0; r < 4; r++) {
    mx[r] = fmaxf(mx[r], __shfl_xor(mx[r], 1, 64));
    mx[r] = fmaxf(mx[r], __shfl_xor(mx[r], 2, 64));
    mx[r] = fmaxf(mx[r], __shfl_xor(mx[r], 4, 64));
    mx[r] = fmaxf(mx[r], __shfl_xor(mx[r], 8, 64));
  }
  float sum[4] = {0.f, 0.f, 0.f, 0.f};
  #pragma unroll
  for (int kt = 0; kt < 14; ++kt) {
    if (kt < nk16) {
      bool valid = (kt * 16 + lr) < L;
      #pragma unroll
      for (int r = 0; r < 4; r++) {
        float p = valid ? __expf(SC * (c[kt][r] - mx[r])) : 0.f;
        sum[r] += p;
        c[kt][r] = p;
      }
    }
  }
  #pragma unroll
  for (int r = 0; r < 4; r++) {
    sum[r] += __shfl_xor(sum[r], 1, 64);
    sum[r] += __shfl_xor(sum[r], 2, 64);
    sum[r] += __shfl_xor(sum[r], 4, 64);
    sum[r] += __shfl_xor(sum[r], 8, 64);
  }

  const int nk16w = nkt * 2;
  #pragma unroll
  for (int kt = 0; kt < 14; ++kt) {
    if (kt < nk16w) {
      #pragma unroll
      for (int r = 0; r < 4; r++)
        SP[(hi * 4 + r) * 232 + kt * 16 + lr] = f2bf(c[kt][r]);
    }
  }
  __syncthreads();

  f32x4 o0 = {0.f, 0.f, 0.f, 0.f}, o1 = o0, o2 = o0;
  const ushort* vbase = Vt + (size_t)bh * 48 * TP;
  #pragma unroll
  for (int kt = 0; kt < 7; ++kt) {
    if (kt < nkt) {
      short8v pa = *(const short8v*)((const char*)SP + lr * 464 + kt * 64 + hi * 16);
      const ushort* vb = vbase + kt * 32 + hi * 8;
      short8v v0 = *(const short8v*)(vb + (size_t)lr * TP);
      short8v v1 = *(const short8v*)(vb + (size_t)(16 + lr) * TP);
      short8v v2 = *(const short8v*)(vb + (size_t)(32 + lr) * TP);
      o0 = __builtin_amdgcn_mfma_f32_16x16x32_bf16(pa, v0, o0, 0, 0, 0);
      o1 = __builtin_amdgcn_mfma_f32_16x16x32_bf16(pa, v1, o1, 0, 0, 0);
      o2 = __builtin_amdgcn_mfma_f32_16x16x32_bf16(pa, v2, o2, 0, 0, 0);
    }
  }

  #pragma unroll
  for (int r = 0; r < 4; r++) {
    int t = q0 + hi * 4 + r;
    if (t < T_LEN) {
      float inv = 1.0f / sum[r];
      ushort* op = o16 + ((size_t)b * TP + t) * D_TR + h * 40;
      op[lr]      = f2bf(o0[r] * inv);
      op[16 + lr] = f2bf(o1[r] * inv);
      if (lr < 8) op[32 + lr] = f2bf(o2[r] * inv);
    }
  }
}

// ---------------- head: (feat scale) -> mlp1 -> logits, one block per b ----------------
__global__ __launch_bounds__(256) void k_head2(const float* __restrict__ featacc,
    const int* __restrict__ lengths, const float* __restrict__ m1w,
    const float* __restrict__ m1b, const float* __restrict__ m2w,
    const float* __restrict__ m2b, float* __restrict__ out) {
  __shared__ float feat[196];
  __shared__ float m1o_s[196];
  __shared__ float r0[4], r1[4];
  const int b = blockIdx.x, tid = threadIdx.x;
  int L = lengths[b]; if (L > T_LEN) L = T_LEN;
  const float inv = 1.0f / (float)(L + 1);
  if (tid < D_FIN)
    feat[tid] = featacc[(size_t)b * D_FIN + tid] * (tid < D_TR ? inv : 1.f);
  __syncthreads();
  if (tid < D_FIN) {
    float s = m1b[tid];
    const float* wr = m1w + (size_t)tid * D_FIN;
    #pragma unroll 4
    for (int k = 0; k < D_FIN; k++) s = fmaf(feat[k], wr[k], s);
    m1o_s[tid] = fmaxf(s, 0.f);
  }
  __syncthreads();
  float p0 = 0.f, p1 = 0.f;
  if (tid < D_FIN) {
    p0 = m1o_s[tid] * m2w[tid];
    p1 = m1o_s[tid] * m2w[D_FIN + tid];
  }
  #pragma unroll
  for (int off = 32; off; off >>= 1) {
    p0 += __shfl_xor(p0, off, 64);
    p1 += __shfl_xor(p1, off, 64);
  }
  int w = tid >> 6;
  if ((tid & 63) == 0) { r0[w] = p0; r1[w] = p1; }
  __syncthreads();
  if (tid == 0) out[2 * b]     = r0[0] + r0[1] + r0[2] + r0[3] + m2b[0];
  if (tid == 1) out[2 * b + 1] = r1[0] + r1[1] + r1[2] + r1[3] + m2b[1];
  if (b == 0 && tid == 2) out[256] = 0.f;  // distance == 0 exactly
}

// ---------------- launch ----------------
extern "C" void kernel_launch(void* const* d_in, const int* in_sizes, int n_in,
                              void* d_out, int out_size, void* d_ws, size_t ws_size,
                              hipStream_t stream) {
  const float* src   = (const float*)d_in[0];
  const float* stat  = (const float*)d_in[1];
  const float* times = (const float*)d_in[2];
  const int*   lens  = (const int*)d_in[3];
  const float* R_u   = (const float*)d_in[4];
  const float* emb_w = (const float*)d_in[5];
  const float* emb_b = (const float*)d_in[6];
  const float* Wv1   = (const float*)d_in[7];
  const float* bv1   = (const float*)d_in[8];
  const float* Wv2   = (const float*)d_in[9];
  const float* bv2   = (const float*)d_in[10];
  const float* ipw   = (const float*)d_in[11];
  const float* ipb   = (const float*)d_in[12];
  const float* ow    = (const float*)d_in[13];
  const float* ob    = (const float*)d_in[14];
  const float* l1w   = (const float*)d_in[15];
  const float* l1b   = (const float*)d_in[16];
  const float* l2w   = (const float*)d_in[17];
  const float* l2b   = (const float*)d_in[18];
  const float* ln1s  = (const float*)d_in[19];
  const float* ln1bb = (const float*)d_in[20];
  const float* ln2s  = (const float*)d_in[21];
  const float* ln2bb = (const float*)d_in[22];
  const float* m1w   = (const float*)d_in[23];
  const float* m1b   = (const float*)d_in[24];
  const float* m2w   = (const float*)d_in[25];
  const float* m2b   = (const float*)d_in[26];
  float* out = (float*)d_out;

  // ---- workspace layout (bytes) ----
  char* p = (char*)d_ws;
  ushort* x16    = (ushort*)p;  p += 9175040;   // 28672 x 160 bf16 (b-major)
  ushort* obuf16 = (ushort*)p;  p += 9175040;   // 28672 x 160 bf16 (b-major)
  ushort* wv1b   = (ushort*)p;  p += 1492992;   // 864 x 864 bf16
  ushort* wv2b   = (ushort*)p;  p += 1492992;
  ushort* ipwb   = (ushort*)p;  p += 307200;    // 2 x 480 x 160
  ushort* owb    = (ushort*)p;  p += 102400;    // 2 x 160 x 160
  ushort* l1wb   = (ushort*)p;  p += 81920;     // 2 x 128 x 160
  ushort* l2wb   = (ushort*)p;  p += 81920;     // 2 x 160 x 128
  float*  featacc= (float*)p;   p += 100352;    // 128 x 196 fp32
  char*   R2     = p;
  ushort* xb16   = (ushort*)R2;                  // phase A: 4608 x 864 bf16 (7.96 MB)
  ushort* V1b    = (ushort*)(R2 + 7962624);      // phase A: 4608 x 860 bf16 (7.93 MB)
  ushort* qkvB   = (ushort*)R2;                  // phase B: 128 x 224 x 480 bf16 (27.5 MB)
  ushort* Vt     = (ushort*)(R2 + 27525120);     // 512 x 48 x 224 bf16 (11 MB)

  k_prep<<<7898, 256, 0, stream>>>(Wv1, Wv2, ipw, ow, l1w, l2w, src, R_u,
                                   stat, emb_w, emb_b,
                                   wv1b, wv2b, ipwb, owb, l1wb, l2wb,
                                   featacc, obuf16, xb16);

  // V1b = bf16(relu(xb @ Wv1^T + bv1)), BN=64 -> 504 blocks (2/CU)
  gemm_bf16<1, 1, 64><<<dim3(14, 36, 1), 256, 0, stream>>>(
      xb16, wv1b, bv1, V1b, KPG, 860, 860, 27);
  k_graphtail<<<128, 256, 0, stream>>>(V1b, wv2b, bv2, times, x16);

  for (int l = 0; l < 2; l++) {
    gemm_qkv<<<dim3(4, 224, 1), 256, 0, stream>>>(
        x16, ipwb + (size_t)l * 76800, ipb + l * 480, qkvB, Vt, 5);
    k_attn4<<<dim3(512, 14), 64, 0, stream>>>(qkvB, Vt, lens, obuf16);
    gemm_lnff<<<448, 256, 0, stream>>>(
        obuf16, owb + (size_t)l * 25600, ob + l * 160,
        ln1s + l * 160, ln1bb + l * 160,
        l1wb + (size_t)l * 20480, l1b + l * 128,
        l2wb + (size_t)l * 20480, l2b + l * 160,
        ln2s + l * 160, ln2bb + l * 160,
        x16, lens, (l == 1) ? featacc : nullptr);
  }

  k_head2<<<128, 256, 0, stream>>>(featacc, lens, m1w, m1b, m2w, m2b, out);
}

// Round 14
// 225.322 us; speedup vs baseline: 3.0289x; 3.0289x over previous
//
#include <hip/hip_runtime.h>
#include <math.h>

#define T_LEN 215
#define TP    224   // padded T (14 * 16)
#define B_N   128
#define DINP  36
#define D_TR  160
#define HD    40
#define D_FIN 196
#define KPG   864   // 860 padded to mult of 32

typedef __attribute__((ext_vector_type(8))) short short8v;
typedef __attribute__((ext_vector_type(4))) float f32x4;

__device__ __forceinline__ ushort f2bf(float x) {
  union { float f; unsigned u; } c; c.f = x;
  unsigned r = c.u + 0x7fffu + ((c.u >> 16) & 1u);
  return (ushort)(r >> 16);
}
__device__ __forceinline__ float bf2f(ushort h) {
  union { unsigned u; float f; } c; c.u = ((unsigned)h) << 16;
  return c.f;
}

// ---------------- mega-prep: weight converts + zeros + emb + xb16 ----------------
__global__ __launch_bounds__(256) void k_prep(const float* __restrict__ Wv1,
    const float* __restrict__ Wv2, const float* __restrict__ ipw, const float* __restrict__ ow,
    const float* __restrict__ l1w, const float* __restrict__ l2w,
    const float* __restrict__ src, const float* __restrict__ R_u,
    const float* __restrict__ stat, const float* __restrict__ emb_w, const float* __restrict__ emb_b,
    ushort* __restrict__ wv1b, ushort* __restrict__ wv2b, ushort* __restrict__ ipwb,
    ushort* __restrict__ owb, ushort* __restrict__ l1wb, ushort* __restrict__ l2wb,
    float* __restrict__ v2acc, float* __restrict__ featacc,
    ushort* __restrict__ obuf16, ushort* __restrict__ xb16) {
  __shared__ float Ss[T_LEN * DINP];
  if (blockIdx.x >= 8202) {   // ---- xb16 path (one block per b) ----
    const int b = blockIdx.x - 8202, tid = threadIdx.x;
    for (int i = tid; i < T_LEN * DINP; i += 256) {
      int t = i / DINP, j = i - t * DINP;
      Ss[i] = src[((size_t)t * B_N + b) * 72 + j];
    }
    __syncthreads();
    for (int i = tid; i < DINP * T_LEN; i += 256) {
      int ii = i / T_LEN, t = i - ii * T_LEN;
      float v = Ss[t * DINP + ii];
      float4 r = ((const float4*)R_u)[ii];
      ushort4 o;
      o.x = f2bf(fmaxf(v * r.x, 0.f)); o.y = f2bf(fmaxf(v * r.y, 0.f));
      o.z = f2bf(fmaxf(v * r.z, 0.f)); o.w = f2bf(fmaxf(v * r.w, 0.f));
      ushort* row = xb16 + (size_t)(b * DINP + ii) * KPG;
      *(ushort4*)(row + 4 * t) = o;
      if (t == 0) { ushort4 z = {0, 0, 0, 0}; *(ushort4*)(row + 860) = z; }
    }
    return;
  }
  int i = blockIdx.x * 256 + threadIdx.x;
  if (i < 746496) { int n = i / KPG, k = i % KPG;
    wv1b[i] = (n < 860 && k < 860) ? f2bf(Wv1[n * 860 + k]) : (ushort)0; return; }
  i -= 746496;
  if (i < 746496) { int n = i / KPG, k = i % KPG;
    wv2b[i] = (n < 860 && k < 860) ? f2bf(Wv2[n * 860 + k]) : (ushort)0; return; }
  i -= 746496;
  if (i < 153600) { ipwb[i] = f2bf(ipw[i]); return; }
  i -= 153600;
  if (i < 51200)  { owb[i] = f2bf(ow[i]); return; }
  i -= 51200;
  if (i < 40960)  { l1wb[i] = f2bf(l1w[i]); return; }
  i -= 40960;
  if (i < 40960)  { l2wb[i] = f2bf(l2w[i]); return; }
  i -= 40960;
  if (i < 110592) { v2acc[i] = 0.f; return; }
  i -= 110592;
  if (i < 20480)  { int b = i / D_TR, d = i - b * D_TR;   // zero featacc cols < 160
    featacc[b * D_FIN + d] = 0.f; return; }
  i -= 20480;
  if (i < 4608)   { int b = i / DINP, ii = i - b * DINP;  // emb -> featacc cols 160..195
    float s = emb_b[ii];
    #pragma unroll
    for (int k = 0; k < 9; k++) s = fmaf(stat[b * 9 + k], emb_w[ii * 9 + k], s);
    featacc[b * D_FIN + D_TR + ii] = s; return; }
  i -= 4608;
  if (i < 184320) {  // zero obuf16 pad rows t in [215,224)
    int b = i / 1440, rem = i % 1440;
    int t = 215 + rem / 160, cc = rem % 160;
    obuf16[((size_t)b * TP + t) * D_TR + cc] = 0; return;
  }
}

// s1_16[b,n] = bf16( (1/36) sum_i V1b[b*36+i, n] ), stride KPG, zero-pad
__global__ __launch_bounds__(256) void k_red_s1(const ushort* __restrict__ V1b, ushort* __restrict__ s1) {
  int idx = blockIdx.x * 256 + threadIdx.x;
  if (idx >= B_N * KPG) return;
  int b = idx / KPG, n = idx % KPG;
  float s = 0.f;
  if (n < 860) {
    #pragma unroll 4
    for (int i = 0; i < DINP; i++) s += bf2f(V1b[((size_t)b * DINP + i) * 860 + n]);
    s *= (1.0f / 36.0f);
  }
  s1[idx] = (n < 860) ? f2bf(s) : (ushort)0;
}

// x16[b,t,*] (b-major) from relu(v2acc + bv2) and inline pe; pad rows zeroed
__global__ __launch_bounds__(256) void k_buildx(const float* __restrict__ v2acc,
    const float* __restrict__ bv2, const float* __restrict__ times,
    ushort* __restrict__ x16) {
  int idx = blockIdx.x * 256 + threadIdx.x;
  if (idx >= B_N * TP * 40) return;
  int c = idx % 40;
  int r = idx / 40;            // r = b*224 + t
  int t = r % TP, b = r / TP;
  float4 f = {0.f, 0.f, 0.f, 0.f};
  if (t < T_LEN) {
    if (c < 36) {
      float4 a = *(const float4*)&v2acc[(size_t)b * KPG + 4 * t];
      float4 bb = *(const float4*)&bv2[4 * t];
      f.x = fmaxf(a.x + bb.x, 0.f); f.y = fmaxf(a.y + bb.y, 0.f);
      f.z = fmaxf(a.z + bb.z, 0.f); f.w = fmaxf(a.w + bb.w, 0.f);
    } else {
      float tm = times[t * B_N + b];
      int j0 = (c - 36) * 4;
      bool is_sin = j0 < 8;
      int kb = j0 & 7;
      float o[4];
      #pragma unroll
      for (int qq = 0; qq < 4; qq++) {
        float ts = expf((float)(kb + qq) * 0.76723400f);  // 215^(k/7)
        float sc = tm / ts;
        o[qq] = is_sin ? sinf(sc) : cosf(sc);
      }
      f.x = o[0]; f.y = o[1]; f.z = o[2]; f.w = o[3];
    }
  }
  ushort4 h = {f2bf(f.x), f2bf(f.y), f2bf(f.z), f2bf(f.w)};
  *(ushort4*)(x16 + (size_t)r * D_TR + 4 * c) = h;
}

// ---------------- bf16 MFMA GEMM: C = act(A[M,KP] @ W[N,KP]^T + bias), BN templated ----------------
template <int RELU, int SPLIT, int WMODE, int BNT>
__global__ __launch_bounds__(256) void gemm_bf16(const ushort* __restrict__ A,
    const ushort* __restrict__ W, const float* __restrict__ bias, void* __restrict__ Cv,
    int KP, int ldc, int ncols, int kts) {
  __shared__ ushort As[128 * 32];
  __shared__ ushort Ws[BNT * 32];
  constexpr int NJ = BNT / 16;
  const int tid = threadIdx.x;
  const int wave = tid >> 6, lane = tid & 63;
  const int lr = lane & 15, hi = lane >> 4;
  const int m0 = blockIdx.y * 128, n0 = blockIdx.x * BNT;
  const int kt0 = blockIdx.z * kts;

  f32x4 acc[2][NJ];
  #pragma unroll
  for (int i = 0; i < 2; i++)
    #pragma unroll
    for (int j = 0; j < NJ; j++) acc[i][j] = (f32x4){0.f, 0.f, 0.f, 0.f};

  const int ar = tid >> 2, g = tid & 3;
  const size_t abase0 = (size_t)(m0 + ar) * KP;
  const size_t abase1 = (size_t)(m0 + ar + 64) * KP;
  const size_t bbase0 = (size_t)(n0 + ar) * KP;
  const size_t bbase1 = (size_t)(n0 + ar + 64) * KP;
  const int awb0 = ar * 64 + ((g * 16) ^ ((ar & 3) << 4));
  const int awb1 = awb0 + 64 * 64;

  const int arow0 = wave * 32 + lr;
  const int arb0 = arow0 * 64 + ((hi * 16) ^ ((arow0 & 3) << 4));
  const int arb1 = (arow0 + 16) * 64 + ((hi * 16) ^ (((arow0 + 16) & 3) << 4));
  int brb[NJ];
  #pragma unroll
  for (int j = 0; j < NJ; j++)
    brb[j] = (j * 16 + lr) * 64 + ((hi * 16) ^ ((lr & 3) << 4));

  for (int kt = 0; kt < kts; ++kt) {
    const int k0 = (kt0 + kt) * 32;
    uint4 va0 = *(const uint4*)(A + abase0 + k0 + g * 8);
    uint4 va1 = *(const uint4*)(A + abase1 + k0 + g * 8);
    uint4 vb0 = *(const uint4*)(W + bbase0 + k0 + g * 8);
    uint4 vb1;
    if constexpr (BNT == 128) vb1 = *(const uint4*)(W + bbase1 + k0 + g * 8);
    if (kt) __syncthreads();
    *(uint4*)((char*)As + awb0) = va0;
    *(uint4*)((char*)As + awb1) = va1;
    *(uint4*)((char*)Ws + awb0) = vb0;
    if constexpr (BNT == 128) *(uint4*)((char*)Ws + awb1) = vb1;
    __syncthreads();
    short8v a0 = *(const short8v*)((const char*)As + arb0);
    short8v a1 = *(const short8v*)((const char*)As + arb1);
    #pragma unroll
    for (int j = 0; j < NJ; j++) {
      short8v bf = *(const short8v*)((const char*)Ws + brb[j]);
      acc[0][j] = __builtin_amdgcn_mfma_f32_16x16x32_bf16(a0, bf, acc[0][j], 0, 0, 0);
      acc[1][j] = __builtin_amdgcn_mfma_f32_16x16x32_bf16(a1, bf, acc[1][j], 0, 0, 0);
    }
  }

  #pragma unroll
  for (int i = 0; i < 2; i++) {
    #pragma unroll
    for (int j = 0; j < NJ; j++) {
      int col = n0 + j * 16 + lr;
      int row = m0 + wave * 32 + i * 16 + hi * 4;
      if (col < ncols) {
        if constexpr (SPLIT) {
          #pragma unroll
          for (int r = 0; r < 4; r++)
            atomicAdd((float*)Cv + (size_t)(row + r) * ldc + col, acc[i][j][r]);
        } else {
          float bb = bias ? bias[col] : 0.f;
          #pragma unroll
          for (int r = 0; r < 4; r++) {
            float xv = acc[i][j][r] + bb;
            if (RELU) xv = fmaxf(xv, 0.f);
            if (WMODE == 0) ((float*)Cv)[(size_t)(row + r) * ldc + col] = xv;
            else            ((ushort*)Cv)[(size_t)(row + r) * ldc + col] = f2bf(xv);
          }
        }
      }
    }
  }
}

// ---------------- qkv GEMM (BN=128): writes Q,K to qkvB[b-major][480]; V transposed to Vt ----------------
__global__ __launch_bounds__(256) void gemm_qkv(const ushort* __restrict__ A,
    const ushort* __restrict__ W, const float* __restrict__ bias,
    ushort* __restrict__ qkvB, ushort* __restrict__ Vt, int kts) {
  __shared__ ushort As[128 * 32];
  __shared__ ushort Ws[128 * 32];
  const int KP = 160;
  const int tid = threadIdx.x;
  const int wave = tid >> 6, lane = tid & 63;
  const int lr = lane & 15, hi = lane >> 4;
  const int m0 = blockIdx.y * 128, n0 = blockIdx.x * 128;

  f32x4 acc[2][8];
  #pragma unroll
  for (int i = 0; i < 2; i++)
    #pragma unroll
    for (int j = 0; j < 8; j++) acc[i][j] = (f32x4){0.f, 0.f, 0.f, 0.f};

  const int ar = tid >> 2, g = tid & 3;
  const size_t abase0 = (size_t)(m0 + ar) * KP;
  const size_t abase1 = (size_t)(m0 + ar + 64) * KP;
  const size_t bbase0 = (size_t)(n0 + ar) * KP;
  const size_t bbase1 = (size_t)(n0 + ar + 64) * KP;
  const int awb0 = ar * 64 + ((g * 16) ^ ((ar & 3) << 4));
  const int awb1 = awb0 + 64 * 64;

  const int arow0 = wave * 32 + lr;
  const int arb0 = arow0 * 64 + ((hi * 16) ^ ((arow0 & 3) << 4));
  const int arb1 = (arow0 + 16) * 64 + ((hi * 16) ^ (((arow0 + 16) & 3) << 4));
  int brb[8];
  #pragma unroll
  for (int j = 0; j < 8; j++)
    brb[j] = (j * 16 + lr) * 64 + ((hi * 16) ^ ((lr & 3) << 4));

  for (int kt = 0; kt < kts; ++kt) {
    const int k0 = kt * 32;
    uint4 va0 = *(const uint4*)(A + abase0 + k0 + g * 8);
    uint4 va1 = *(const uint4*)(A + abase1 + k0 + g * 8);
    uint4 vb0 = *(const uint4*)(W + bbase0 + k0 + g * 8);
    uint4 vb1 = *(const uint4*)(W + bbase1 + k0 + g * 8);
    if (kt) __syncthreads();
    *(uint4*)((char*)As + awb0) = va0;
    *(uint4*)((char*)As + awb1) = va1;
    *(uint4*)((char*)Ws + awb0) = vb0;
    *(uint4*)((char*)Ws + awb1) = vb1;
    __syncthreads();
    short8v a0 = *(const short8v*)((const char*)As + arb0);
    short8v a1 = *(const short8v*)((const char*)As + arb1);
    #pragma unroll
    for (int j = 0; j < 8; j++) {
      short8v bf = *(const short8v*)((const char*)Ws + brb[j]);
      acc[0][j] = __builtin_amdgcn_mfma_f32_16x16x32_bf16(a0, bf, acc[0][j], 0, 0, 0);
      acc[1][j] = __builtin_amdgcn_mfma_f32_16x16x32_bf16(a1, bf, acc[1][j], 0, 0, 0);
    }
  }

  #pragma unroll
  for (int i = 0; i < 2; i++) {
    const int row = m0 + wave * 32 + i * 16 + hi * 4;   // = b*224 + t0 (4 consecutive t)
    const int b = row / TP, t0 = row - b * TP;
    #pragma unroll
    for (int j = 0; j < 8; j++) {
      int col = n0 + j * 16 + lr;
      if (col < 320) {               // Q or K
        float bb = bias[col];
        #pragma unroll
        for (int r = 0; r < 4; r++)
          qkvB[(size_t)(row + r) * 480 + col] = f2bf(acc[i][j][r] + bb);
      } else if (col < 480) {        // V: transposed packed store
        float bb = bias[col];
        int dg = col - 320;
        int hh = dg / 40, dd = dg - hh * 40;
        ushort4 pv;
        pv.x = f2bf(acc[i][j][0] + bb); pv.y = f2bf(acc[i][j][1] + bb);
        pv.z = f2bf(acc[i][j][2] + bb); pv.w = f2bf(acc[i][j][3] + bb);
        *(ushort4*)(Vt + (((size_t)(b * 4 + hh) * 48 + dd) * TP + t0)) = pv;
      }
    }
  }
}

// ---------------- fused layer tail: [attn-out GEMM + res + LN1] -> [FF1] -> [FF2 + res + LN2] ----------------
__global__ __launch_bounds__(256) void gemm_lnff(const ushort* __restrict__ Ao,
    const ushort* __restrict__ Wo, const float* __restrict__ bo,
    const float* __restrict__ g1, const float* __restrict__ be1,
    const ushort* __restrict__ W1, const float* __restrict__ b1,
    const ushort* __restrict__ W2, const float* __restrict__ b2,
    const float* __restrict__ g2, const float* __restrict__ be2,
    ushort* __restrict__ x16, const int* __restrict__ lengths,
    float* __restrict__ featacc) {
  __shared__ ushort As[64 * 32];
  __shared__ ushort Ws[160 * 32];
  __shared__ ushort W1s[128 * 32];
  __shared__ ushort W2s[160 * 32];
  __shared__ ushort Xln[64 * 168];
  __shared__ ushort Hs[64 * 136];
  const int tid = threadIdx.x;
  const int wave = tid >> 6, lane = tid & 63;
  const int lr = lane & 15, hi = lane >> 4;
  const int m0 = blockIdx.x * 64;

  const int ar = tid >> 2, g = tid & 3;
  const int awb = ar * 64 + ((g * 16) ^ ((ar & 3) << 4));
  const int awb1 = awb + 64 * 64;
  const int wr0 = tid >> 2,         ws0 = tid & 3;
  const int wr1 = (tid + 256) >> 2, ws1 = (tid + 256) & 3;
  const int wr2 = (tid + 512) >> 2, ws2 = (tid + 512) & 3;
  const int wwb0 = wr0 * 64 + ((ws0 * 16) ^ ((wr0 & 3) << 4));
  const int wwb1 = wr1 * 64 + ((ws1 * 16) ^ ((wr1 & 3) << 4));
  const int wwb2 = wr2 * 64 + ((ws2 * 16) ^ ((wr2 & 3) << 4));
  const int arow = wave * 16 + lr;
  const int arb = arow * 64 + ((hi * 16) ^ ((arow & 3) << 4));
  int brb[10];
  #pragma unroll
  for (int j = 0; j < 10; j++)
    brb[j] = (j * 16 + lr) * 64 + ((hi * 16) ^ ((lr & 3) << 4));

  const int lrow0 = wave * 16 + hi * 4;
  const int rb = m0 + lrow0;

  // ======== phase A: attn-out GEMM (K=160) + bias + residual + LN1 -> Xln ========
  {
    f32x4 acc[10];
    #pragma unroll
    for (int j = 0; j < 10; j++) acc[j] = (f32x4){0.f, 0.f, 0.f, 0.f};
    const size_t abase = (size_t)(m0 + ar) * 160;
    for (int kt = 0; kt < 5; ++kt) {
      const int k0 = kt * 32;
      uint4 va = *(const uint4*)(Ao + abase + k0 + g * 8);
      uint4 w0 = *(const uint4*)(Wo + (size_t)wr0 * 160 + k0 + ws0 * 8);
      uint4 w1 = *(const uint4*)(Wo + (size_t)wr1 * 160 + k0 + ws1 * 8);
      uint4 w2;
      if (tid < 128) w2 = *(const uint4*)(Wo + (size_t)wr2 * 160 + k0 + ws2 * 8);
      if (kt) __syncthreads();
      *(uint4*)((char*)As + awb) = va;
      *(uint4*)((char*)Ws + wwb0) = w0;
      *(uint4*)((char*)Ws + wwb1) = w1;
      if (tid < 128) *(uint4*)((char*)Ws + wwb2) = w2;
      __syncthreads();
      short8v a0 = *(const short8v*)((const char*)As + arb);
      #pragma unroll
      for (int j = 0; j < 10; j++) {
        short8v bf = *(const short8v*)((const char*)Ws + brb[j]);
        acc[j] = __builtin_amdgcn_mfma_f32_16x16x32_bf16(a0, bf, acc[j], 0, 0, 0);
      }
    }
    float s[4] = {0.f, 0.f, 0.f, 0.f};
    #pragma unroll
    for (int j = 0; j < 10; j++) {
      const int col = j * 16 + lr;
      const float bb = bo[col];
      #pragma unroll
      for (int r = 0; r < 4; r++) {
        float v = acc[j][r] + bb + bf2f(x16[(size_t)(rb + r) * D_TR + col]);
        acc[j][r] = v;
        s[r] += v;
      }
    }
    #pragma unroll
    for (int r = 0; r < 4; r++) {
      s[r] += __shfl_xor(s[r], 1, 64);
      s[r] += __shfl_xor(s[r], 2, 64);
      s[r] += __shfl_xor(s[r], 4, 64);
      s[r] += __shfl_xor(s[r], 8, 64);
    }
    float mu[4], q2[4] = {0.f, 0.f, 0.f, 0.f};
    #pragma unroll
    for (int r = 0; r < 4; r++) mu[r] = s[r] * (1.0f / 160.0f);
    #pragma unroll
    for (int j = 0; j < 10; j++)
      #pragma unroll
      for (int r = 0; r < 4; r++) {
        float d = acc[j][r] - mu[r];
        q2[r] += d * d;
      }
    #pragma unroll
    for (int r = 0; r < 4; r++) {
      q2[r] += __shfl_xor(q2[r], 1, 64);
      q2[r] += __shfl_xor(q2[r], 2, 64);
      q2[r] += __shfl_xor(q2[r], 4, 64);
      q2[r] += __shfl_xor(q2[r], 8, 64);
    }
    float rstd[4];
    #pragma unroll
    for (int r = 0; r < 4; r++) rstd[r] = rsqrtf(q2[r] * (1.0f / 160.0f) + 1e-5f);
    #pragma unroll
    for (int j = 0; j < 10; j++) {
      const int col = j * 16 + lr;
      const float gc = g1[col], bc = be1[col];
      #pragma unroll
      for (int r = 0; r < 4; r++) {
        float o = (acc[j][r] - mu[r]) * rstd[r] * gc + bc;
        Xln[(lrow0 + r) * 168 + col] = f2bf(o);
      }
    }
  }
  __syncthreads();

  // ======== phase B: h = relu(Xln @ W1^T + b1) -> Hs ========
  {
    f32x4 acc1[8];
    #pragma unroll
    for (int j = 0; j < 8; j++) acc1[j] = (f32x4){0.f, 0.f, 0.f, 0.f};
    int brb8[8];
    #pragma unroll
    for (int j = 0; j < 8; j++)
      brb8[j] = (j * 16 + lr) * 64 + ((hi * 16) ^ ((lr & 3) << 4));
    for (int kt = 0; kt < 5; ++kt) {
      const int k0 = kt * 32;
      uint4 w10 = *(const uint4*)(W1 + (size_t)ar * 160 + k0 + g * 8);
      uint4 w11 = *(const uint4*)(W1 + (size_t)(ar + 64) * 160 + k0 + g * 8);
      if (kt) __syncthreads();
      *(uint4*)((char*)W1s + awb) = w10;
      *(uint4*)((char*)W1s + awb1) = w11;
      __syncthreads();
      short8v a0 = *(const short8v*)(&Xln[(wave * 16 + lr) * 168 + k0 + hi * 8]);
      #pragma unroll
      for (int j = 0; j < 8; j++) {
        short8v bf = *(const short8v*)((const char*)W1s + brb8[j]);
        acc1[j] = __builtin_amdgcn_mfma_f32_16x16x32_bf16(a0, bf, acc1[j], 0, 0, 0);
      }
    }
    #pragma unroll
    for (int j = 0; j < 8; j++) {
      const int col = j * 16 + lr;
      const float bb = b1[col];
      #pragma unroll
      for (int r = 0; r < 4; r++)
        Hs[(lrow0 + r) * 136 + col] = f2bf(fmaxf(acc1[j][r] + bb, 0.f));
    }
  }
  __syncthreads();

  // ======== phase C: o = Hs @ W2^T + b2; + Xln residual + LN2 -> x16 / featacc ========
  {
    f32x4 acc[10];
    #pragma unroll
    for (int j = 0; j < 10; j++) acc[j] = (f32x4){0.f, 0.f, 0.f, 0.f};
    for (int kt = 0; kt < 4; ++kt) {
      const int k0 = kt * 32;
      uint4 w0 = *(const uint4*)(W2 + (size_t)wr0 * 128 + k0 + ws0 * 8);
      uint4 w1 = *(const uint4*)(W2 + (size_t)wr1 * 128 + k0 + ws1 * 8);
      uint4 w2;
      if (tid < 128) w2 = *(const uint4*)(W2 + (size_t)wr2 * 128 + k0 + ws2 * 8);
      if (kt) __syncthreads();
      *(uint4*)((char*)W2s + wwb0) = w0;
      *(uint4*)((char*)W2s + wwb1) = w1;
      if (tid < 128) *(uint4*)((char*)W2s + wwb2) = w2;
      __syncthreads();
      short8v a0 = *(const short8v*)(&Hs[(wave * 16 + lr) * 136 + k0 + hi * 8]);
      #pragma unroll
      for (int j = 0; j < 10; j++) {
        short8v bf = *(const short8v*)((const char*)W2s + brb[j]);
        acc[j] = __builtin_amdgcn_mfma_f32_16x16x32_bf16(a0, bf, acc[j], 0, 0, 0);
      }
    }
    float s[4] = {0.f, 0.f, 0.f, 0.f};
    #pragma unroll
    for (int j = 0; j < 10; j++) {
      const int col = j * 16 + lr;
      const float bb = b2[col];
      #pragma unroll
      for (int r = 0; r < 4; r++) {
        float v = acc[j][r] + bb + bf2f(Xln[(lrow0 + r) * 168 + col]);
        acc[j][r] = v;
        s[r] += v;
      }
    }
    #pragma unroll
    for (int r = 0; r < 4; r++) {
      s[r] += __shfl_xor(s[r], 1, 64);
      s[r] += __shfl_xor(s[r], 2, 64);
      s[r] += __shfl_xor(s[r], 4, 64);
      s[r] += __shfl_xor(s[r], 8, 64);
    }
    float mu[4], q2[4] = {0.f, 0.f, 0.f, 0.f};
    #pragma unroll
    for (int r = 0; r < 4; r++) mu[r] = s[r] * (1.0f / 160.0f);
    #pragma unroll
    for (int j = 0; j < 10; j++)
      #pragma unroll
      for (int r = 0; r < 4; r++) {
        float d = acc[j][r] - mu[r];
        q2[r] += d * d;
      }
    #pragma unroll
    for (int r = 0; r < 4; r++) {
      q2[r] += __shfl_xor(q2[r], 1, 64);
      q2[r] += __shfl_xor(q2[r], 2, 64);
      q2[r] += __shfl_xor(q2[r], 4, 64);
      q2[r] += __shfl_xor(q2[r], 8, 64);
    }
    float rstd[4];
    #pragma unroll
    for (int r = 0; r < 4; r++) rstd[r] = rsqrtf(q2[r] * (1.0f / 160.0f) + 1e-5f);

    if (featacc == nullptr) {
      #pragma unroll
      for (int j = 0; j < 10; j++) {
        const int col = j * 16 + lr;
        const float gc = g2[col], bc = be2[col];
        #pragma unroll
        for (int r = 0; r < 4; r++) {
          float o = (acc[j][r] - mu[r]) * rstd[r] * gc + bc;
          x16[(size_t)(rb + r) * D_TR + col] = f2bf(o);
        }
      }
    } else {
      const int b = rb / TP, t0 = rb - b * TP;
      int L = lengths[b]; if (L > T_LEN) L = T_LEN;
      #pragma unroll
      for (int j = 0; j < 10; j++) {
        const int col = j * 16 + lr;
        const float gc = g2[col], bc = be2[col];
        float sacc = 0.f;
        #pragma unroll
        for (int r = 0; r < 4; r++) {
          float o = (acc[j][r] - mu[r]) * rstd[r] * gc + bc;
          if (t0 + r < L) sacc += o;
        }
        if (t0 < L) atomicAdd(&featacc[b * D_FIN + col], sacc);
      }
    }
  }
}

// ---------------- barrier-free 1-wave flash attention (b-major qkv + Vt) ----------------
__global__ __launch_bounds__(64) void k_attn4(const ushort* __restrict__ qkvB,
    const ushort* __restrict__ Vt, const int* __restrict__ lengths,
    ushort* __restrict__ o16) {
  __shared__ ushort SP[16 * 232];
  const int bh = blockIdx.x;
  const int b = bh >> 2, h = bh & 3;
  int L = lengths[b]; if (L > T_LEN) L = T_LEN;
  const int q0 = blockIdx.y << 4;
  if (q0 >= L) return;
  const int lane = threadIdx.x;
  const int lr = lane & 15, hi = lane >> 4;
  const int nk16 = (L + 15) >> 4;
  const int nkt  = (L + 31) >> 5;
  const float SC = 0.15811388300841898f;  // 1/sqrt(40)

  const ushort* qrow = qkvB + ((size_t)b * TP + q0) * 480 + h * 40;
  uint4 qa0u = *(const uint4*)(qrow + lr * 480 + hi * 8);
  uint4 qa1u = {0, 0, 0, 0};
  if (hi == 0) qa1u = *(const uint4*)(qrow + lr * 480 + 32);
  short8v qa0 = *(short8v*)&qa0u;
  short8v qa1 = *(short8v*)&qa1u;

  f32x4 c[14];
  #pragma unroll
  for (int kt = 0; kt < 14; ++kt) {
    c[kt] = (f32x4){0.f, 0.f, 0.f, 0.f};
    if (kt < nk16) {
      const ushort* krow = qkvB + ((size_t)b * TP + kt * 16) * 480 + 160 + h * 40;
      uint4 kb0u = *(const uint4*)(krow + lr * 480 + hi * 8);
      uint4 kb1u = {0, 0, 0, 0};
      if (hi == 0) kb1u = *(const uint4*)(krow + lr * 480 + 32);
      c[kt] = __builtin_amdgcn_mfma_f32_16x16x32_bf16(qa0, *(short8v*)&kb0u, c[kt], 0, 0, 0);
      c[kt] = __builtin_amdgcn_mfma_f32_16x16x32_bf16(qa1, *(short8v*)&kb1u, c[kt], 0, 0, 0);
    }
  }

  float mx[4] = {-1e30f, -1e30f, -1e30f, -1e30f};
  #pragma unroll
  for (int kt = 0; kt < 14; ++kt) {
    if (kt < nk16) {
      bool valid = (kt * 16 + lr) < L;
      #pragma unroll
      for (int r = 0; r < 4; r++) {
        float v = valid ? c[kt][r] : -1e30f;
        mx[r] = fmaxf(mx[r], v);
      }
    }
  }
  #pragma unroll
  for (int r = 0; r < 4; r++) {
    mx[r] = fmaxf(mx[r], __shfl_xor(mx[r], 1, 64));
    mx[r] = fmaxf(mx[r], __shfl_xor(mx[r], 2, 64));
    mx[r] = fmaxf(mx[r], __shfl_xor(mx[r], 4, 64));
    mx[r] = fmaxf(mx[r], __shfl_xor(mx[r], 8, 64));
  }
  float sum[4] = {0.f, 0.f, 0.f, 0.f};
  #pragma unroll
  for (int kt = 0; kt < 14; ++kt) {
    if (kt < nk16) {
      bool valid = (kt * 16 + lr) < L;
      #pragma unroll
      for (int r = 0; r < 4; r++) {
        float p = valid ? __expf(SC * (c[kt][r] - mx[r])) : 0.f;
        sum[r] += p;
        c[kt][r] = p;
      }
    }
  }
  #pragma unroll
  for (int r = 0; r < 4; r++) {
    sum[r] += __shfl_xor(sum[r], 1, 64);
    sum[r] += __shfl_xor(sum[r], 2, 64);
    sum[r] += __shfl_xor(sum[r], 4, 64);
    sum[r] += __shfl_xor(sum[r], 8, 64);
  }

  const int nk16w = nkt * 2;
  #pragma unroll
  for (int kt = 0; kt < 14; ++kt) {
    if (kt < nk16w) {
      #pragma unroll
      for (int r = 0; r < 4; r++)
        SP[(hi * 4 + r) * 232 + kt * 16 + lr] = f2bf(c[kt][r]);
    }
  }
  __syncthreads();

  f32x4 o0 = {0.f, 0.f, 0.f, 0.f}, o1 = o0, o2 = o0;
  const ushort* vbase = Vt + (size_t)bh * 48 * TP;
  #pragma unroll
  for (int kt = 0; kt < 7; ++kt) {
    if (kt < nkt) {
      short8v pa = *(const short8v*)((const char*)SP + lr * 464 + kt * 64 + hi * 16);
      const ushort* vb = vbase + kt * 32 + hi * 8;
      short8v v0 = *(const short8v*)(vb + (size_t)lr * TP);
      short8v v1 = *(const short8v*)(vb + (size_t)(16 + lr) * TP);
      short8v v2 = *(const short8v*)(vb + (size_t)(32 + lr) * TP);
      o0 = __builtin_amdgcn_mfma_f32_16x16x32_bf16(pa, v0, o0, 0, 0, 0);
      o1 = __builtin_amdgcn_mfma_f32_16x16x32_bf16(pa, v1, o1, 0, 0, 0);
      o2 = __builtin_amdgcn_mfma_f32_16x16x32_bf16(pa, v2, o2, 0, 0, 0);
    }
  }

  #pragma unroll
  for (int r = 0; r < 4; r++) {
    int t = q0 + hi * 4 + r;
    if (t < T_LEN) {
      float inv = 1.0f / sum[r];
      ushort* op = o16 + ((size_t)b * TP + t) * D_TR + h * 40;
      op[lr]      = f2bf(o0[r] * inv);
      op[16 + lr] = f2bf(o1[r] * inv);
      if (lr < 8) op[32 + lr] = f2bf(o2[r] * inv);
    }
  }
}

// ---------------- head: (feat scale) -> mlp1 -> logits, one block per b ----------------
__global__ __launch_bounds__(256) void k_head2(const float* __restrict__ featacc,
    const int* __restrict__ lengths, const float* __restrict__ m1w,
    const float* __restrict__ m1b, const float* __restrict__ m2w,
    const float* __restrict__ m2b, float* __restrict__ out) {
  __shared__ float feat[196];
  __shared__ float m1o_s[196];
  __shared__ float r0[4], r1[4];
  const int b = blockIdx.x, tid = threadIdx.x;
  int L = lengths[b]; if (L > T_LEN) L = T_LEN;
  const float inv = 1.0f / (float)(L + 1);
  if (tid < D_FIN)
    feat[tid] = featacc[(size_t)b * D_FIN + tid] * (tid < D_TR ? inv : 1.f);
  __syncthreads();
  if (tid < D_FIN) {
    float s = m1b[tid];
    const float* wr = m1w + (size_t)tid * D_FIN;
    #pragma unroll 4
    for (int k = 0; k < D_FIN; k++) s = fmaf(feat[k], wr[k], s);
    m1o_s[tid] = fmaxf(s, 0.f);
  }
  __syncthreads();
  float p0 = 0.f, p1 = 0.f;
  if (tid < D_FIN) {
    p0 = m1o_s[tid] * m2w[tid];
    p1 = m1o_s[tid] * m2w[D_FIN + tid];
  }
  #pragma unroll
  for (int off = 32; off; off >>= 1) {
    p0 += __shfl_xor(p0, off, 64);
    p1 += __shfl_xor(p1, off, 64);
  }
  int w = tid >> 6;
  if ((tid & 63) == 0) { r0[w] = p0; r1[w] = p1; }
  __syncthreads();
  if (tid == 0) out[2 * b]     = r0[0] + r0[1] + r0[2] + r0[3] + m2b[0];
  if (tid == 1) out[2 * b + 1] = r1[0] + r1[1] + r1[2] + r1[3] + m2b[1];
  if (b == 0 && tid == 2) out[256] = 0.f;  // distance == 0 exactly
}

// ---------------- launch ----------------
extern "C" void kernel_launch(void* const* d_in, const int* in_sizes, int n_in,
                              void* d_out, int out_size, void* d_ws, size_t ws_size,
                              hipStream_t stream) {
  const float* src   = (const float*)d_in[0];
  const float* stat  = (const float*)d_in[1];
  const float* times = (const float*)d_in[2];
  const int*   lens  = (const int*)d_in[3];
  const float* R_u   = (const float*)d_in[4];
  const float* emb_w = (const float*)d_in[5];
  const float* emb_b = (const float*)d_in[6];
  const float* Wv1   = (const float*)d_in[7];
  const float* bv1   = (const float*)d_in[8];
  const float* Wv2   = (const float*)d_in[9];
  const float* bv2   = (const float*)d_in[10];
  const float* ipw   = (const float*)d_in[11];
  const float* ipb   = (const float*)d_in[12];
  const float* ow    = (const float*)d_in[13];
  const float* ob    = (const float*)d_in[14];
  const float* l1w   = (const float*)d_in[15];
  const float* l1b   = (const float*)d_in[16];
  const float* l2w   = (const float*)d_in[17];
  const float* l2b   = (const float*)d_in[18];
  const float* ln1s  = (const float*)d_in[19];
  const float* ln1bb = (const float*)d_in[20];
  const float* ln2s  = (const float*)d_in[21];
  const float* ln2bb = (const float*)d_in[22];
  const float* m1w   = (const float*)d_in[23];
  const float* m1b   = (const float*)d_in[24];
  const float* m2w   = (const float*)d_in[25];
  const float* m2b   = (const float*)d_in[26];
  float* out = (float*)d_out;

  // ---- workspace layout (bytes) ----
  char* p = (char*)d_ws;
  ushort* x16    = (ushort*)p;  p += 9175040;   // 28672 x 160 bf16 (b-major)
  float*  v2acc  = (float*)p;   p += 442368;    // 128 x 864 fp32
  ushort* s1b    = (ushort*)p;  p += 221184;    // 128 x 864 bf16
  ushort* obuf16 = (ushort*)p;  p += 9175040;   // 28672 x 160 bf16 (b-major)
  ushort* wv1b   = (ushort*)p;  p += 1492992;   // 864 x 864 bf16
  ushort* wv2b   = (ushort*)p;  p += 1492992;
  ushort* ipwb   = (ushort*)p;  p += 307200;    // 2 x 480 x 160
  ushort* owb    = (ushort*)p;  p += 102400;    // 2 x 160 x 160
  ushort* l1wb   = (ushort*)p;  p += 81920;     // 2 x 128 x 160
  ushort* l2wb   = (ushort*)p;  p += 81920;     // 2 x 160 x 128
  float*  featacc= (float*)p;   p += 100352;    // 128 x 196 fp32
  char*   R2     = p;
  ushort* xb16   = (ushort*)R2;                  // phase A: 4608 x 864 bf16 (7.96 MB)
  ushort* V1b    = (ushort*)(R2 + 7962624);      // phase A: 4608 x 860 bf16 (7.93 MB)
  ushort* qkvB   = (ushort*)R2;                  // phase B: 128 x 224 x 480 bf16 (27.5 MB)
  ushort* Vt     = (ushort*)(R2 + 27525120);     // 512 x 48 x 224 bf16 (11 MB)

  k_prep<<<8330, 256, 0, stream>>>(Wv1, Wv2, ipw, ow, l1w, l2w, src, R_u,
                                   stat, emb_w, emb_b,
                                   wv1b, wv2b, ipwb, owb, l1wb, l2wb,
                                   v2acc, featacc, obuf16, xb16);

  // V1b = bf16(relu(xb @ Wv1^T + bv1)), BN=128 — streaming stores
  gemm_bf16<1, 0, 1, 128><<<dim3(7, 36, 1), 256, 0, stream>>>(
      xb16, wv1b, bv1, V1b, KPG, 860, 860, 27);
  k_red_s1<<<432, 256, 0, stream>>>(V1b, s1b);
  gemm_bf16<0, 1, 0, 64><<<dim3(14, 1, 9), 256, 0, stream>>>(
      s1b, wv2b, nullptr, v2acc, KPG, KPG, KPG, 3);
  k_buildx<<<4480, 256, 0, stream>>>(v2acc, bv2, times, x16);

  for (int l = 0; l < 2; l++) {
    gemm_qkv<<<dim3(4, 224, 1), 256, 0, stream>>>(
        x16, ipwb + (size_t)l * 76800, ipb + l * 480, qkvB, Vt, 5);
    k_attn4<<<dim3(512, 14), 64, 0, stream>>>(qkvB, Vt, lens, obuf16);
    gemm_lnff<<<448, 256, 0, stream>>>(
        obuf16, owb + (size_t)l * 25600, ob + l * 160,
        ln1s + l * 160, ln1bb + l * 160,
        l1wb + (size_t)l * 20480, l1b + l * 128,
        l2wb + (size_t)l * 20480, l2b + l * 160,
        ln2s + l * 160, ln2bb + l * 160,
        x16, lens, (l == 1) ? featacc : nullptr);
  }

  k_head2<<<128, 256, 0, stream>>>(featacc, lens, m1w, m1b, m2w, m2b, out);
}

// Round 15
// 220.415 us; speedup vs baseline: 3.0964x; 1.0223x over previous
//
#include <hip/hip_runtime.h>
#include <math.h>

#define T_LEN 215
#define TP    224   // padded T (14 * 16)
#define B_N   128
#define DINP  36
#define D_TR  160
#define HD    40
#define D_FIN 196
#define KPG   864   // 860 padded to mult of 32

typedef __attribute__((ext_vector_type(8))) short short8v;
typedef __attribute__((ext_vector_type(4))) float f32x4;

__device__ __forceinline__ ushort f2bf(float x) {
  union { float f; unsigned u; } c; c.f = x;
  unsigned r = c.u + 0x7fffu + ((c.u >> 16) & 1u);
  return (ushort)(r >> 16);
}
__device__ __forceinline__ float bf2f(ushort h) {
  union { unsigned u; float f; } c; c.u = ((unsigned)h) << 16;
  return c.f;
}

// ---------------- mega-prep: weight converts + zeros + emb + xb16 ----------------
__global__ __launch_bounds__(256) void k_prep(const float* __restrict__ Wv1,
    const float* __restrict__ Wv2, const float* __restrict__ ipw, const float* __restrict__ ow,
    const float* __restrict__ l1w, const float* __restrict__ l2w,
    const float* __restrict__ src, const float* __restrict__ R_u,
    const float* __restrict__ stat, const float* __restrict__ emb_w, const float* __restrict__ emb_b,
    ushort* __restrict__ wv1b, ushort* __restrict__ wv2b, ushort* __restrict__ ipwb,
    ushort* __restrict__ owb, ushort* __restrict__ l1wb, ushort* __restrict__ l2wb,
    float* __restrict__ v2acc, float* __restrict__ featacc,
    ushort* __restrict__ obuf16, ushort* __restrict__ xb16) {
  __shared__ float Ss[T_LEN * DINP];
  if (blockIdx.x >= 8202) {   // ---- xb16 path (one block per b) ----
    const int b = blockIdx.x - 8202, tid = threadIdx.x;
    for (int i = tid; i < T_LEN * DINP; i += 256) {
      int t = i / DINP, j = i - t * DINP;
      Ss[i] = src[((size_t)t * B_N + b) * 72 + j];
    }
    __syncthreads();
    for (int i = tid; i < DINP * T_LEN; i += 256) {
      int ii = i / T_LEN, t = i - ii * T_LEN;
      float v = Ss[t * DINP + ii];
      float4 r = ((const float4*)R_u)[ii];
      ushort4 o;
      o.x = f2bf(fmaxf(v * r.x, 0.f)); o.y = f2bf(fmaxf(v * r.y, 0.f));
      o.z = f2bf(fmaxf(v * r.z, 0.f)); o.w = f2bf(fmaxf(v * r.w, 0.f));
      ushort* row = xb16 + (size_t)(b * DINP + ii) * KPG;
      *(ushort4*)(row + 4 * t) = o;
      if (t == 0) { ushort4 z = {0, 0, 0, 0}; *(ushort4*)(row + 860) = z; }
    }
    return;
  }
  int i = blockIdx.x * 256 + threadIdx.x;
  if (i < 746496) { int n = i / KPG, k = i % KPG;
    wv1b[i] = (n < 860 && k < 860) ? f2bf(Wv1[n * 860 + k]) : (ushort)0; return; }
  i -= 746496;
  if (i < 746496) { int n = i / KPG, k = i % KPG;
    wv2b[i] = (n < 860 && k < 860) ? f2bf(Wv2[n * 860 + k]) : (ushort)0; return; }
  i -= 746496;
  if (i < 153600) { ipwb[i] = f2bf(ipw[i]); return; }
  i -= 153600;
  if (i < 51200)  { owb[i] = f2bf(ow[i]); return; }
  i -= 51200;
  if (i < 40960)  { l1wb[i] = f2bf(l1w[i]); return; }
  i -= 40960;
  if (i < 40960)  { l2wb[i] = f2bf(l2w[i]); return; }
  i -= 40960;
  if (i < 110592) { v2acc[i] = 0.f; return; }
  i -= 110592;
  if (i < 20480)  { int b = i / D_TR, d = i - b * D_TR;   // zero featacc cols < 160
    featacc[b * D_FIN + d] = 0.f; return; }
  i -= 20480;
  if (i < 4608)   { int b = i / DINP, ii = i - b * DINP;  // emb -> featacc cols 160..195
    float s = emb_b[ii];
    #pragma unroll
    for (int k = 0; k < 9; k++) s = fmaf(stat[b * 9 + k], emb_w[ii * 9 + k], s);
    featacc[b * D_FIN + D_TR + ii] = s; return; }
  i -= 4608;
  if (i < 184320) {  // zero obuf16 pad rows t in [215,224)
    int b = i / 1440, rem = i % 1440;
    int t = 215 + rem / 160, cc = rem % 160;
    obuf16[((size_t)b * TP + t) * D_TR + cc] = 0; return;
  }
}

// s1_16[b,n] = bf16( (1/36) sum_i V1b[b*36+i, n] ), stride KPG, zero-pad
__global__ __launch_bounds__(256) void k_red_s1(const ushort* __restrict__ V1b, ushort* __restrict__ s1) {
  int idx = blockIdx.x * 256 + threadIdx.x;
  if (idx >= B_N * KPG) return;
  int b = idx / KPG, n = idx % KPG;
  float s = 0.f;
  if (n < 860) {
    #pragma unroll 4
    for (int i = 0; i < DINP; i++) s += bf2f(V1b[((size_t)b * DINP + i) * 860 + n]);
    s *= (1.0f / 36.0f);
  }
  s1[idx] = (n < 860) ? f2bf(s) : (ushort)0;
}

// x16[b,t,*] (b-major) from relu(v2acc + bv2) and inline pe; pad rows zeroed
__global__ __launch_bounds__(256) void k_buildx(const float* __restrict__ v2acc,
    const float* __restrict__ bv2, const float* __restrict__ times,
    ushort* __restrict__ x16) {
  int idx = blockIdx.x * 256 + threadIdx.x;
  if (idx >= B_N * TP * 40) return;
  int c = idx % 40;
  int r = idx / 40;            // r = b*224 + t
  int t = r % TP, b = r / TP;
  float4 f = {0.f, 0.f, 0.f, 0.f};
  if (t < T_LEN) {
    if (c < 36) {
      float4 a = *(const float4*)&v2acc[(size_t)b * KPG + 4 * t];
      float4 bb = *(const float4*)&bv2[4 * t];
      f.x = fmaxf(a.x + bb.x, 0.f); f.y = fmaxf(a.y + bb.y, 0.f);
      f.z = fmaxf(a.z + bb.z, 0.f); f.w = fmaxf(a.w + bb.w, 0.f);
    } else {
      float tm = times[t * B_N + b];
      int j0 = (c - 36) * 4;
      bool is_sin = j0 < 8;
      int kb = j0 & 7;
      float o[4];
      #pragma unroll
      for (int qq = 0; qq < 4; qq++) {
        float ts = expf((float)(kb + qq) * 0.76723400f);  // 215^(k/7)
        float sc = tm / ts;
        o[qq] = is_sin ? sinf(sc) : cosf(sc);
      }
      f.x = o[0]; f.y = o[1]; f.z = o[2]; f.w = o[3];
    }
  }
  ushort4 h = {f2bf(f.x), f2bf(f.y), f2bf(f.z), f2bf(f.w)};
  *(ushort4*)(x16 + (size_t)r * D_TR + 4 * c) = h;
}

// ---------------- bf16 MFMA GEMM: C = act(A[M,KP] @ W[N,KP]^T + bias), BN templated ----------------
template <int RELU, int SPLIT, int WMODE, int BNT>
__global__ __launch_bounds__(256) void gemm_bf16(const ushort* __restrict__ A,
    const ushort* __restrict__ W, const float* __restrict__ bias, void* __restrict__ Cv,
    int KP, int ldc, int ncols, int kts) {
  __shared__ ushort As[128 * 32];
  __shared__ ushort Ws[BNT * 32];
  constexpr int NJ = BNT / 16;
  const int tid = threadIdx.x;
  const int wave = tid >> 6, lane = tid & 63;
  const int lr = lane & 15, hi = lane >> 4;
  const int m0 = blockIdx.y * 128, n0 = blockIdx.x * BNT;
  const int kt0 = blockIdx.z * kts;

  f32x4 acc[2][NJ];
  #pragma unroll
  for (int i = 0; i < 2; i++)
    #pragma unroll
    for (int j = 0; j < NJ; j++) acc[i][j] = (f32x4){0.f, 0.f, 0.f, 0.f};

  const int ar = tid >> 2, g = tid & 3;
  const size_t abase0 = (size_t)(m0 + ar) * KP;
  const size_t abase1 = (size_t)(m0 + ar + 64) * KP;
  const size_t bbase0 = (size_t)(n0 + ar) * KP;
  const size_t bbase1 = (size_t)(n0 + ar + 64) * KP;
  const int awb0 = ar * 64 + ((g * 16) ^ ((ar & 3) << 4));
  const int awb1 = awb0 + 64 * 64;

  const int arow0 = wave * 32 + lr;
  const int arb0 = arow0 * 64 + ((hi * 16) ^ ((arow0 & 3) << 4));
  const int arb1 = (arow0 + 16) * 64 + ((hi * 16) ^ (((arow0 + 16) & 3) << 4));
  int brb[NJ];
  #pragma unroll
  for (int j = 0; j < NJ; j++)
    brb[j] = (j * 16 + lr) * 64 + ((hi * 16) ^ ((lr & 3) << 4));

  for (int kt = 0; kt < kts; ++kt) {
    const int k0 = (kt0 + kt) * 32;
    uint4 va0 = *(const uint4*)(A + abase0 + k0 + g * 8);
    uint4 va1 = *(const uint4*)(A + abase1 + k0 + g * 8);
    uint4 vb0 = *(const uint4*)(W + bbase0 + k0 + g * 8);
    uint4 vb1;
    if constexpr (BNT == 128) vb1 = *(const uint4*)(W + bbase1 + k0 + g * 8);
    if (kt) __syncthreads();
    *(uint4*)((char*)As + awb0) = va0;
    *(uint4*)((char*)As + awb1) = va1;
    *(uint4*)((char*)Ws + awb0) = vb0;
    if constexpr (BNT == 128) *(uint4*)((char*)Ws + awb1) = vb1;
    __syncthreads();
    short8v a0 = *(const short8v*)((const char*)As + arb0);
    short8v a1 = *(const short8v*)((const char*)As + arb1);
    #pragma unroll
    for (int j = 0; j < NJ; j++) {
      short8v bf = *(const short8v*)((const char*)Ws + brb[j]);
      acc[0][j] = __builtin_amdgcn_mfma_f32_16x16x32_bf16(a0, bf, acc[0][j], 0, 0, 0);
      acc[1][j] = __builtin_amdgcn_mfma_f32_16x16x32_bf16(a1, bf, acc[1][j], 0, 0, 0);
    }
  }

  #pragma unroll
  for (int i = 0; i < 2; i++) {
    #pragma unroll
    for (int j = 0; j < NJ; j++) {
      int col = n0 + j * 16 + lr;
      int row = m0 + wave * 32 + i * 16 + hi * 4;
      if (col < ncols) {
        if constexpr (SPLIT) {
          #pragma unroll
          for (int r = 0; r < 4; r++)
            atomicAdd((float*)Cv + (size_t)(row + r) * ldc + col, acc[i][j][r]);
        } else {
          float bb = bias ? bias[col] : 0.f;
          #pragma unroll
          for (int r = 0; r < 4; r++) {
            float xv = acc[i][j][r] + bb;
            if (RELU) xv = fmaxf(xv, 0.f);
            if (WMODE == 0) ((float*)Cv)[(size_t)(row + r) * ldc + col] = xv;
            else            ((ushort*)Cv)[(size_t)(row + r) * ldc + col] = f2bf(xv);
          }
        }
      }
    }
  }
}

// ---------------- qkv GEMM (BN=128): writes Q,K to qkvB[b-major][480]; V transposed to Vt ----------------
__global__ __launch_bounds__(256) void gemm_qkv(const ushort* __restrict__ A,
    const ushort* __restrict__ W, const float* __restrict__ bias,
    ushort* __restrict__ qkvB, ushort* __restrict__ Vt, int kts) {
  __shared__ ushort As[128 * 32];
  __shared__ ushort Ws[128 * 32];
  const int KP = 160;
  const int tid = threadIdx.x;
  const int wave = tid >> 6, lane = tid & 63;
  const int lr = lane & 15, hi = lane >> 4;
  const int m0 = blockIdx.y * 128, n0 = blockIdx.x * 128;

  f32x4 acc[2][8];
  #pragma unroll
  for (int i = 0; i < 2; i++)
    #pragma unroll
    for (int j = 0; j < 8; j++) acc[i][j] = (f32x4){0.f, 0.f, 0.f, 0.f};

  const int ar = tid >> 2, g = tid & 3;
  const size_t abase0 = (size_t)(m0 + ar) * KP;
  const size_t abase1 = (size_t)(m0 + ar + 64) * KP;
  const size_t bbase0 = (size_t)(n0 + ar) * KP;
  const size_t bbase1 = (size_t)(n0 + ar + 64) * KP;
  const int awb0 = ar * 64 + ((g * 16) ^ ((ar & 3) << 4));
  const int awb1 = awb0 + 64 * 64;

  const int arow0 = wave * 32 + lr;
  const int arb0 = arow0 * 64 + ((hi * 16) ^ ((arow0 & 3) << 4));
  const int arb1 = (arow0 + 16) * 64 + ((hi * 16) ^ (((arow0 + 16) & 3) << 4));
  int brb[8];
  #pragma unroll
  for (int j = 0; j < 8; j++)
    brb[j] = (j * 16 + lr) * 64 + ((hi * 16) ^ ((lr & 3) << 4));

  for (int kt = 0; kt < kts; ++kt) {
    const int k0 = kt * 32;
    uint4 va0 = *(const uint4*)(A + abase0 + k0 + g * 8);
    uint4 va1 = *(const uint4*)(A + abase1 + k0 + g * 8);
    uint4 vb0 = *(const uint4*)(W + bbase0 + k0 + g * 8);
    uint4 vb1 = *(const uint4*)(W + bbase1 + k0 + g * 8);
    if (kt) __syncthreads();
    *(uint4*)((char*)As + awb0) = va0;
    *(uint4*)((char*)As + awb1) = va1;
    *(uint4*)((char*)Ws + awb0) = vb0;
    *(uint4*)((char*)Ws + awb1) = vb1;
    __syncthreads();
    short8v a0 = *(const short8v*)((const char*)As + arb0);
    short8v a1 = *(const short8v*)((const char*)As + arb1);
    #pragma unroll
    for (int j = 0; j < 8; j++) {
      short8v bf = *(const short8v*)((const char*)Ws + brb[j]);
      acc[0][j] = __builtin_amdgcn_mfma_f32_16x16x32_bf16(a0, bf, acc[0][j], 0, 0, 0);
      acc[1][j] = __builtin_amdgcn_mfma_f32_16x16x32_bf16(a1, bf, acc[1][j], 0, 0, 0);
    }
  }

  #pragma unroll
  for (int i = 0; i < 2; i++) {
    const int row = m0 + wave * 32 + i * 16 + hi * 4;   // = b*224 + t0 (4 consecutive t)
    const int b = row / TP, t0 = row - b * TP;
    #pragma unroll
    for (int j = 0; j < 8; j++) {
      int col = n0 + j * 16 + lr;
      if (col < 320) {               // Q or K
        float bb = bias[col];
        #pragma unroll
        for (int r = 0; r < 4; r++)
          qkvB[(size_t)(row + r) * 480 + col] = f2bf(acc[i][j][r] + bb);
      } else if (col < 480) {        // V: transposed packed store
        float bb = bias[col];
        int dg = col - 320;
        int hh = dg / 40, dd = dg - hh * 40;
        ushort4 pv;
        pv.x = f2bf(acc[i][j][0] + bb); pv.y = f2bf(acc[i][j][1] + bb);
        pv.z = f2bf(acc[i][j][2] + bb); pv.w = f2bf(acc[i][j][3] + bb);
        *(ushort4*)(Vt + (((size_t)(b * 4 + hh) * 48 + dd) * TP + t0)) = pv;
      }
    }
  }
}

// ---------------- fused layer tail: [attn-out GEMM + res + LN1] -> [FF1] -> [FF2 + res + LN2] ----------------
__global__ __launch_bounds__(256) void gemm_lnff(const ushort* __restrict__ Ao,
    const ushort* __restrict__ Wo, const float* __restrict__ bo,
    const float* __restrict__ g1, const float* __restrict__ be1,
    const ushort* __restrict__ W1, const float* __restrict__ b1,
    const ushort* __restrict__ W2, const float* __restrict__ b2,
    const float* __restrict__ g2, const float* __restrict__ be2,
    ushort* __restrict__ x16, const int* __restrict__ lengths,
    float* __restrict__ featacc) {
  __shared__ ushort As[64 * 32];
  __shared__ ushort Ws[160 * 32];
  __shared__ ushort W1s[128 * 32];
  __shared__ ushort W2s[160 * 32];
  __shared__ ushort Xln[64 * 168];
  __shared__ ushort Hs[64 * 136];
  const int tid = threadIdx.x;
  const int wave = tid >> 6, lane = tid & 63;
  const int lr = lane & 15, hi = lane >> 4;
  const int m0 = blockIdx.x * 64;

  const int ar = tid >> 2, g = tid & 3;
  const int awb = ar * 64 + ((g * 16) ^ ((ar & 3) << 4));
  const int awb1 = awb + 64 * 64;
  const int wr0 = tid >> 2,         ws0 = tid & 3;
  const int wr1 = (tid + 256) >> 2, ws1 = (tid + 256) & 3;
  const int wr2 = (tid + 512) >> 2, ws2 = (tid + 512) & 3;
  const int wwb0 = wr0 * 64 + ((ws0 * 16) ^ ((wr0 & 3) << 4));
  const int wwb1 = wr1 * 64 + ((ws1 * 16) ^ ((wr1 & 3) << 4));
  const int wwb2 = wr2 * 64 + ((ws2 * 16) ^ ((wr2 & 3) << 4));
  const int arow = wave * 16 + lr;
  const int arb = arow * 64 + ((hi * 16) ^ ((arow & 3) << 4));
  int brb[10];
  #pragma unroll
  for (int j = 0; j < 10; j++)
    brb[j] = (j * 16 + lr) * 64 + ((hi * 16) ^ ((lr & 3) << 4));

  const int lrow0 = wave * 16 + hi * 4;
  const int rb = m0 + lrow0;

  // ======== phase A: attn-out GEMM (K=160) + bias + residual + LN1 -> Xln ========
  {
    f32x4 acc[10];
    #pragma unroll
    for (int j = 0; j < 10; j++) acc[j] = (f32x4){0.f, 0.f, 0.f, 0.f};
    const size_t abase = (size_t)(m0 + ar) * 160;
    for (int kt = 0; kt < 5; ++kt) {
      const int k0 = kt * 32;
      uint4 va = *(const uint4*)(Ao + abase + k0 + g * 8);
      uint4 w0 = *(const uint4*)(Wo + (size_t)wr0 * 160 + k0 + ws0 * 8);
      uint4 w1 = *(const uint4*)(Wo + (size_t)wr1 * 160 + k0 + ws1 * 8);
      uint4 w2;
      if (tid < 128) w2 = *(const uint4*)(Wo + (size_t)wr2 * 160 + k0 + ws2 * 8);
      if (kt) __syncthreads();
      *(uint4*)((char*)As + awb) = va;
      *(uint4*)((char*)Ws + wwb0) = w0;
      *(uint4*)((char*)Ws + wwb1) = w1;
      if (tid < 128) *(uint4*)((char*)Ws + wwb2) = w2;
      __syncthreads();
      short8v a0 = *(const short8v*)((const char*)As + arb);
      #pragma unroll
      for (int j = 0; j < 10; j++) {
        short8v bf = *(const short8v*)((const char*)Ws + brb[j]);
        acc[j] = __builtin_amdgcn_mfma_f32_16x16x32_bf16(a0, bf, acc[j], 0, 0, 0);
      }
    }
    float s[4] = {0.f, 0.f, 0.f, 0.f};
    #pragma unroll
    for (int j = 0; j < 10; j++) {
      const int col = j * 16 + lr;
      const float bb = bo[col];
      #pragma unroll
      for (int r = 0; r < 4; r++) {
        float v = acc[j][r] + bb + bf2f(x16[(size_t)(rb + r) * D_TR + col]);
        acc[j][r] = v;
        s[r] += v;
      }
    }
    #pragma unroll
    for (int r = 0; r < 4; r++) {
      s[r] += __shfl_xor(s[r], 1, 64);
      s[r] += __shfl_xor(s[r], 2, 64);
      s[r] += __shfl_xor(s[r], 4, 64);
      s[r] += __shfl_xor(s[r], 8, 64);
    }
    float mu[4], q2[4] = {0.f, 0.f, 0.f, 0.f};
    #pragma unroll
    for (int r = 0; r < 4; r++) mu[r] = s[r] * (1.0f / 160.0f);
    #pragma unroll
    for (int j = 0; j < 10; j++)
      #pragma unroll
      for (int r = 0; r < 4; r++) {
        float d = acc[j][r] - mu[r];
        q2[r] += d * d;
      }
    #pragma unroll
    for (int r = 0; r < 4; r++) {
      q2[r] += __shfl_xor(q2[r], 1, 64);
      q2[r] += __shfl_xor(q2[r], 2, 64);
      q2[r] += __shfl_xor(q2[r], 4, 64);
      q2[r] += __shfl_xor(q2[r], 8, 64);
    }
    float rstd[4];
    #pragma unroll
    for (int r = 0; r < 4; r++) rstd[r] = rsqrtf(q2[r] * (1.0f / 160.0f) + 1e-5f);
    #pragma unroll
    for (int j = 0; j < 10; j++) {
      const int col = j * 16 + lr;
      const float gc = g1[col], bc = be1[col];
      #pragma unroll
      for (int r = 0; r < 4; r++) {
        float o = (acc[j][r] - mu[r]) * rstd[r] * gc + bc;
        Xln[(lrow0 + r) * 168 + col] = f2bf(o);
      }
    }
  }
  __syncthreads();

  // ======== phase B: h = relu(Xln @ W1^T + b1) -> Hs ========
  {
    f32x4 acc1[8];
    #pragma unroll
    for (int j = 0; j < 8; j++) acc1[j] = (f32x4){0.f, 0.f, 0.f, 0.f};
    int brb8[8];
    #pragma unroll
    for (int j = 0; j < 8; j++)
      brb8[j] = (j * 16 + lr) * 64 + ((hi * 16) ^ ((lr & 3) << 4));
    for (int kt = 0; kt < 5; ++kt) {
      const int k0 = kt * 32;
      uint4 w10 = *(const uint4*)(W1 + (size_t)ar * 160 + k0 + g * 8);
      uint4 w11 = *(const uint4*)(W1 + (size_t)(ar + 64) * 160 + k0 + g * 8);
      if (kt) __syncthreads();
      *(uint4*)((char*)W1s + awb) = w10;
      *(uint4*)((char*)W1s + awb1) = w11;
      __syncthreads();
      short8v a0 = *(const short8v*)(&Xln[(wave * 16 + lr) * 168 + k0 + hi * 8]);
      #pragma unroll
      for (int j = 0; j < 8; j++) {
        short8v bf = *(const short8v*)((const char*)W1s + brb8[j]);
        acc1[j] = __builtin_amdgcn_mfma_f32_16x16x32_bf16(a0, bf, acc1[j], 0, 0, 0);
      }
    }
    #pragma unroll
    for (int j = 0; j < 8; j++) {
      const int col = j * 16 + lr;
      const float bb = b1[col];
      #pragma unroll
      for (int r = 0; r < 4; r++)
        Hs[(lrow0 + r) * 136 + col] = f2bf(fmaxf(acc1[j][r] + bb, 0.f));
    }
  }
  __syncthreads();

  // ======== phase C: o = Hs @ W2^T + b2; + Xln residual + LN2 -> x16 / featacc ========
  {
    f32x4 acc[10];
    #pragma unroll
    for (int j = 0; j < 10; j++) acc[j] = (f32x4){0.f, 0.f, 0.f, 0.f};
    for (int kt = 0; kt < 4; ++kt) {
      const int k0 = kt * 32;
      uint4 w0 = *(const uint4*)(W2 + (size_t)wr0 * 128 + k0 + ws0 * 8);
      uint4 w1 = *(const uint4*)(W2 + (size_t)wr1 * 128 + k0 + ws1 * 8);
      uint4 w2;
      if (tid < 128) w2 = *(const uint4*)(W2 + (size_t)wr2 * 128 + k0 + ws2 * 8);
      if (kt) __syncthreads();
      *(uint4*)((char*)W2s + wwb0) = w0;
      *(uint4*)((char*)W2s + wwb1) = w1;
      if (tid < 128) *(uint4*)((char*)W2s + wwb2) = w2;
      __syncthreads();
      short8v a0 = *(const short8v*)(&Hs[(wave * 16 + lr) * 136 + k0 + hi * 8]);
      #pragma unroll
      for (int j = 0; j < 10; j++) {
        short8v bf = *(const short8v*)((const char*)W2s + brb[j]);
        acc[j] = __builtin_amdgcn_mfma_f32_16x16x32_bf16(a0, bf, acc[j], 0, 0, 0);
      }
    }
    float s[4] = {0.f, 0.f, 0.f, 0.f};
    #pragma unroll
    for (int j = 0; j < 10; j++) {
      const int col = j * 16 + lr;
      const float bb = b2[col];
      #pragma unroll
      for (int r = 0; r < 4; r++) {
        float v = acc[j][r] + bb + bf2f(Xln[(lrow0 + r) * 168 + col]);
        acc[j][r] = v;
        s[r] += v;
      }
    }
    #pragma unroll
    for (int r = 0; r < 4; r++) {
      s[r] += __shfl_xor(s[r], 1, 64);
      s[r] += __shfl_xor(s[r], 2, 64);
      s[r] += __shfl_xor(s[r], 4, 64);
      s[r] += __shfl_xor(s[r], 8, 64);
    }
    float mu[4], q2[4] = {0.f, 0.f, 0.f, 0.f};
    #pragma unroll
    for (int r = 0; r < 4; r++) mu[r] = s[r] * (1.0f / 160.0f);
    #pragma unroll
    for (int j = 0; j < 10; j++)
      #pragma unroll
      for (int r = 0; r < 4; r++) {
        float d = acc[j][r] - mu[r];
        q2[r] += d * d;
      }
    #pragma unroll
    for (int r = 0; r < 4; r++) {
      q2[r] += __shfl_xor(q2[r], 1, 64);
      q2[r] += __shfl_xor(q2[r], 2, 64);
      q2[r] += __shfl_xor(q2[r], 4, 64);
      q2[r] += __shfl_xor(q2[r], 8, 64);
    }
    float rstd[4];
    #pragma unroll
    for (int r = 0; r < 4; r++) rstd[r] = rsqrtf(q2[r] * (1.0f / 160.0f) + 1e-5f);

    if (featacc == nullptr) {
      #pragma unroll
      for (int j = 0; j < 10; j++) {
        const int col = j * 16 + lr;
        const float gc = g2[col], bc = be2[col];
        #pragma unroll
        for (int r = 0; r < 4; r++) {
          float o = (acc[j][r] - mu[r]) * rstd[r] * gc + bc;
          x16[(size_t)(rb + r) * D_TR + col] = f2bf(o);
        }
      }
    } else {
      const int b = rb / TP, t0 = rb - b * TP;
      int L = lengths[b]; if (L > T_LEN) L = T_LEN;
      #pragma unroll
      for (int j = 0; j < 10; j++) {
        const int col = j * 16 + lr;
        const float gc = g2[col], bc = be2[col];
        float sacc = 0.f;
        #pragma unroll
        for (int r = 0; r < 4; r++) {
          float o = (acc[j][r] - mu[r]) * rstd[r] * gc + bc;
          if (t0 + r < L) sacc += o;
        }
        if (t0 < L) atomicAdd(&featacc[b * D_FIN + col], sacc);
      }
    }
  }
}

// ---------------- barrier-free 1-wave flash attention (b-major qkv + Vt) ----------------
__global__ __launch_bounds__(64) void k_attn4(const ushort* __restrict__ qkvB,
    const ushort* __restrict__ Vt, const int* __restrict__ lengths,
    ushort* __restrict__ o16) {
  __shared__ ushort SP[16 * 232];
  const int bh = blockIdx.x;
  const int b = bh >> 2, h = bh & 3;
  int L = lengths[b]; if (L > T_LEN) L = T_LEN;
  const int q0 = blockIdx.y << 4;
  if (q0 >= L) return;
  const int lane = threadIdx.x;
  const int lr = lane & 15, hi = lane >> 4;
  const int nk16 = (L + 15) >> 4;
  const int nkt  = (L + 31) >> 5;
  const float SC = 0.15811388300841898f;  // 1/sqrt(40)

  const ushort* qrow = qkvB + ((size_t)b * TP + q0) * 480 + h * 40;
  uint4 qa0u = *(const uint4*)(qrow + lr * 480 + hi * 8);
  uint4 qa1u = {0, 0, 0, 0};
  if (hi == 0) qa1u = *(const uint4*)(qrow + lr * 480 + 32);
  short8v qa0 = *(short8v*)&qa0u;
  short8v qa1 = *(short8v*)&qa1u;

  f32x4 c[14];
  #pragma unroll
  for (int kt = 0; kt < 14; ++kt) {
    c[kt] = (f32x4){0.f, 0.f, 0.f, 0.f};
    if (kt < nk16) {
      const ushort* krow = qkvB + ((size_t)b * TP + kt * 16) * 480 + 160 + h * 40;
      uint4 kb0u = *(const uint4*)(krow + lr * 480 + hi * 8);
      uint4 kb1u = {0, 0, 0, 0};
      if (hi == 0) kb1u = *(const uint4*)(krow + lr * 480 + 32);
      c[kt] = __builtin_amdgcn_mfma_f32_16x16x32_bf16(qa0, *(short8v*)&kb0u, c[kt], 0, 0, 0);
      c[kt] = __builtin_amdgcn_mfma_f32_16x16x32_bf16(qa1, *(short8v*)&kb1u, c[kt], 0, 0, 0);
    }
  }

  float mx[4] = {-1e30f, -1e30f, -1e30f, -1e30f};
  #pragma unroll
  for (int kt = 0; kt < 14; ++kt) {
    if (kt < nk16) {
      bool valid = (kt * 16 + lr) < L;
      #pragma unroll
      for (int r = 0; r < 4; r++) {
        float v = valid ? c[kt][r] : -1e30f;
        mx[r] = fmaxf(mx[r], v);
      }
    }
  }
  #pragma unroll
  for (int r = 0; r < 4; r++) {
    mx[r] = fmaxf(mx[r], __shfl_xor(mx[r], 1, 64));
    mx[r] = fmaxf(mx[r], __shfl_xor(mx[r], 2, 64));
    mx[r] = fmaxf(mx[r], __shfl_xor(mx[r], 4, 64));
    mx[r] = fmaxf(mx[r], __shfl_xor(mx[r], 8, 64));
  }
  float sum[4] = {0.f, 0.f, 0.f, 0.f};
  #pragma unroll
  for (int kt = 0; kt < 14; ++kt) {
    if (kt < nk16) {
      bool valid = (kt * 16 + lr) < L;
      #pragma unroll
      for (int r = 0; r < 4; r++) {
        float p = valid ? __expf(SC * (c[kt][r] - mx[r])) : 0.f;
        sum[r] += p;
        c[kt][r] = p;
      }
    }
  }
  #pragma unroll
  for (int r = 0; r < 4; r++) {
    sum[r] += __shfl_xor(sum[r], 1, 64);
    sum[r] += __shfl_xor(sum[r], 2, 64);
    sum[r] += __shfl_xor(sum[r], 4, 64);
    sum[r] += __shfl_xor(sum[r], 8, 64);
  }

  const int nk16w = nkt * 2;
  #pragma unroll
  for (int kt = 0; kt < 14; ++kt) {
    if (kt < nk16w) {
      #pragma unroll
      for (int r = 0; r < 4; r++)
        SP[(hi * 4 + r) * 232 + kt * 16 + lr] = f2bf(c[kt][r]);
    }
  }
  __syncthreads();

  f32x4 o0 = {0.f, 0.f, 0.f, 0.f}, o1 = o0, o2 = o0;
  const ushort* vbase = Vt + (size_t)bh * 48 * TP;
  #pragma unroll
  for (int kt = 0; kt < 7; ++kt) {
    if (kt < nkt) {
      short8v pa = *(const short8v*)((const char*)SP + lr * 464 + kt * 64 + hi * 16);
      const ushort* vb = vbase + kt * 32 + hi * 8;
      short8v v0 = *(const short8v*)(vb + (size_t)lr * TP);
      short8v v1 = *(const short8v*)(vb + (size_t)(16 + lr) * TP);
      short8v v2 = *(const short8v*)(vb + (size_t)(32 + lr) * TP);
      o0 = __builtin_amdgcn_mfma_f32_16x16x32_bf16(pa, v0, o0, 0, 0, 0);
      o1 = __builtin_amdgcn_mfma_f32_16x16x32_bf16(pa, v1, o1, 0, 0, 0);
      o2 = __builtin_amdgcn_mfma_f32_16x16x32_bf16(pa, v2, o2, 0, 0, 0);
    }
  }

  #pragma unroll
  for (int r = 0; r < 4; r++) {
    int t = q0 + hi * 4 + r;
    if (t < T_LEN) {
      float inv = 1.0f / sum[r];
      ushort* op = o16 + ((size_t)b * TP + t) * D_TR + h * 40;
      op[lr]      = f2bf(o0[r] * inv);
      op[16 + lr] = f2bf(o1[r] * inv);
      if (lr < 8) op[32 + lr] = f2bf(o2[r] * inv);
    }
  }
}

// ---------------- head: (feat scale) -> mlp1 -> logits, one block per b ----------------
__global__ __launch_bounds__(256) void k_head2(const float* __restrict__ featacc,
    const int* __restrict__ lengths, const float* __restrict__ m1w,
    const float* __restrict__ m1b, const float* __restrict__ m2w,
    const float* __restrict__ m2b, float* __restrict__ out) {
  __shared__ float feat[196];
  __shared__ float m1o_s[196];
  __shared__ float r0[4], r1[4];
  const int b = blockIdx.x, tid = threadIdx.x;
  int L = lengths[b]; if (L > T_LEN) L = T_LEN;
  const float inv = 1.0f / (float)(L + 1);
  if (tid < D_FIN)
    feat[tid] = featacc[(size_t)b * D_FIN + tid] * (tid < D_TR ? inv : 1.f);
  __syncthreads();
  if (tid < D_FIN) {
    float s = m1b[tid];
    const float* wr = m1w + (size_t)tid * D_FIN;
    #pragma unroll 4
    for (int k = 0; k < D_FIN; k++) s = fmaf(feat[k], wr[k], s);
    m1o_s[tid] = fmaxf(s, 0.f);
  }
  __syncthreads();
  float p0 = 0.f, p1 = 0.f;
  if (tid < D_FIN) {
    p0 = m1o_s[tid] * m2w[tid];
    p1 = m1o_s[tid] * m2w[D_FIN + tid];
  }
  #pragma unroll
  for (int off = 32; off; off >>= 1) {
    p0 += __shfl_xor(p0, off, 64);
    p1 += __shfl_xor(p1, off, 64);
  }
  int w = tid >> 6;
  if ((tid & 63) == 0) { r0[w] = p0; r1[w] = p1; }
  __syncthreads();
  if (tid == 0) out[2 * b]     = r0[0] + r0[1] + r0[2] + r0[3] + m2b[0];
  if (tid == 1) out[2 * b + 1] = r1[0] + r1[1] + r1[2] + r1[3] + m2b[1];
  if (b == 0 && tid == 2) out[256] = 0.f;  // distance == 0 exactly
}

// ---------------- launch ----------------
extern "C" void kernel_launch(void* const* d_in, const int* in_sizes, int n_in,
                              void* d_out, int out_size, void* d_ws, size_t ws_size,
                              hipStream_t stream) {
  const float* src   = (const float*)d_in[0];
  const float* stat  = (const float*)d_in[1];
  const float* times = (const float*)d_in[2];
  const int*   lens  = (const int*)d_in[3];
  const float* R_u   = (const float*)d_in[4];
  const float* emb_w = (const float*)d_in[5];
  const float* emb_b = (const float*)d_in[6];
  const float* Wv1   = (const float*)d_in[7];
  const float* bv1   = (const float*)d_in[8];
  const float* Wv2   = (const float*)d_in[9];
  const float* bv2   = (const float*)d_in[10];
  const float* ipw   = (const float*)d_in[11];
  const float* ipb   = (const float*)d_in[12];
  const float* ow    = (const float*)d_in[13];
  const float* ob    = (const float*)d_in[14];
  const float* l1w   = (const float*)d_in[15];
  const float* l1b   = (const float*)d_in[16];
  const float* l2w   = (const float*)d_in[17];
  const float* l2b   = (const float*)d_in[18];
  const float* ln1s  = (const float*)d_in[19];
  const float* ln1bb = (const float*)d_in[20];
  const float* ln2s  = (const float*)d_in[21];
  const float* ln2bb = (const float*)d_in[22];
  const float* m1w   = (const float*)d_in[23];
  const float* m1b   = (const float*)d_in[24];
  const float* m2w   = (const float*)d_in[25];
  const float* m2b   = (const float*)d_in[26];
  float* out = (float*)d_out;

  // ---- workspace layout (bytes) ----
  char* p = (char*)d_ws;
  ushort* x16    = (ushort*)p;  p += 9175040;   // 28672 x 160 bf16 (b-major)
  float*  v2acc  = (float*)p;   p += 442368;    // 128 x 864 fp32
  ushort* s1b    = (ushort*)p;  p += 221184;    // 128 x 864 bf16
  ushort* obuf16 = (ushort*)p;  p += 9175040;   // 28672 x 160 bf16 (b-major)
  ushort* wv1b   = (ushort*)p;  p += 1492992;   // 864 x 864 bf16
  ushort* wv2b   = (ushort*)p;  p += 1492992;
  ushort* ipwb   = (ushort*)p;  p += 307200;    // 2 x 480 x 160
  ushort* owb    = (ushort*)p;  p += 102400;    // 2 x 160 x 160
  ushort* l1wb   = (ushort*)p;  p += 81920;     // 2 x 128 x 160
  ushort* l2wb   = (ushort*)p;  p += 81920;     // 2 x 160 x 128
  float*  featacc= (float*)p;   p += 100352;    // 128 x 196 fp32
  char*   R2     = p;
  ushort* xb16   = (ushort*)R2;                  // phase A: 4608 x 864 bf16 (7.96 MB)
  ushort* V1b    = (ushort*)(R2 + 7962624);      // phase A: 4608 x 860 bf16 (7.93 MB)
  ushort* qkvB   = (ushort*)R2;                  // phase B: 128 x 224 x 480 bf16 (27.5 MB)
  ushort* Vt     = (ushort*)(R2 + 27525120);     // 512 x 48 x 224 bf16 (11 MB)

  k_prep<<<8330, 256, 0, stream>>>(Wv1, Wv2, ipw, ow, l1w, l2w, src, R_u,
                                   stat, emb_w, emb_b,
                                   wv1b, wv2b, ipwb, owb, l1wb, l2wb,
                                   v2acc, featacc, obuf16, xb16);

  // V1b = bf16(relu(xb @ Wv1^T + bv1)), BN=64 -> 504 blocks (2 blocks/CU for latency hiding)
  gemm_bf16<1, 0, 1, 64><<<dim3(14, 36, 1), 256, 0, stream>>>(
      xb16, wv1b, bv1, V1b, KPG, 860, 860, 27);
  k_red_s1<<<432, 256, 0, stream>>>(V1b, s1b);
  gemm_bf16<0, 1, 0, 64><<<dim3(14, 1, 9), 256, 0, stream>>>(
      s1b, wv2b, nullptr, v2acc, KPG, KPG, KPG, 3);
  k_buildx<<<4480, 256, 0, stream>>>(v2acc, bv2, times, x16);

  for (int l = 0; l < 2; l++) {
    gemm_qkv<<<dim3(4, 224, 1), 256, 0, stream>>>(
        x16, ipwb + (size_t)l * 76800, ipb + l * 480, qkvB, Vt, 5);
    k_attn4<<<dim3(512, 14), 64, 0, stream>>>(qkvB, Vt, lens, obuf16);
    gemm_lnff<<<448, 256, 0, stream>>>(
        obuf16, owb + (size_t)l * 25600, ob + l * 160,
        ln1s + l * 160, ln1bb + l * 160,
        l1wb + (size_t)l * 20480, l1b + l * 128,
        l2wb + (size_t)l * 20480, l2b + l * 160,
        ln2s + l * 160, ln2bb + l * 160,
        x16, lens, (l == 1) ? featacc : nullptr);
  }

  k_head2<<<128, 256, 0, stream>>>(featacc, lens, m1w, m1b, m2w, m2b, out);
}

// Round 16
// 219.699 us; speedup vs baseline: 3.1065x; 1.0033x over previous
//
#include <hip/hip_runtime.h>
#include <math.h>

#define T_LEN 215
#define TP    224   // padded T (14 * 16)
#define B_N   128
#define DINP  36
#define D_TR  160
#define HD    40
#define D_FIN 196
#define KPG   864   // 860 padded to mult of 32

typedef __attribute__((ext_vector_type(8))) short short8v;
typedef __attribute__((ext_vector_type(4))) float f32x4;

__device__ __forceinline__ ushort f2bf(float x) {
  union { float f; unsigned u; } c; c.f = x;
  unsigned r = c.u + 0x7fffu + ((c.u >> 16) & 1u);
  return (ushort)(r >> 16);
}
__device__ __forceinline__ float bf2f(ushort h) {
  union { unsigned u; float f; } c; c.u = ((unsigned)h) << 16;
  return c.f;
}

// ---------------- mega-prep: weight converts + zeros + emb + xb16 ----------------
__global__ __launch_bounds__(256) void k_prep(const float* __restrict__ Wv1,
    const float* __restrict__ Wv2, const float* __restrict__ ipw, const float* __restrict__ ow,
    const float* __restrict__ l1w, const float* __restrict__ l2w,
    const float* __restrict__ src, const float* __restrict__ R_u,
    const float* __restrict__ stat, const float* __restrict__ emb_w, const float* __restrict__ emb_b,
    ushort* __restrict__ wv1b, ushort* __restrict__ wv2b, ushort* __restrict__ ipwb,
    ushort* __restrict__ owb, ushort* __restrict__ l1wb, ushort* __restrict__ l2wb,
    float* __restrict__ v2acc, float* __restrict__ featacc,
    ushort* __restrict__ obuf16, ushort* __restrict__ xb16) {
  __shared__ float Ss[T_LEN * DINP];
  if (blockIdx.x >= 8202) {   // ---- xb16 path (one block per b) ----
    const int b = blockIdx.x - 8202, tid = threadIdx.x;
    for (int i = tid; i < T_LEN * DINP; i += 256) {
      int t = i / DINP, j = i - t * DINP;
      Ss[i] = src[((size_t)t * B_N + b) * 72 + j];
    }
    __syncthreads();
    for (int i = tid; i < DINP * T_LEN; i += 256) {
      int ii = i / T_LEN, t = i - ii * T_LEN;
      float v = Ss[t * DINP + ii];
      float4 r = ((const float4*)R_u)[ii];
      ushort4 o;
      o.x = f2bf(fmaxf(v * r.x, 0.f)); o.y = f2bf(fmaxf(v * r.y, 0.f));
      o.z = f2bf(fmaxf(v * r.z, 0.f)); o.w = f2bf(fmaxf(v * r.w, 0.f));
      ushort* row = xb16 + (size_t)(b * DINP + ii) * KPG;
      *(ushort4*)(row + 4 * t) = o;
      if (t == 0) { ushort4 z = {0, 0, 0, 0}; *(ushort4*)(row + 860) = z; }
    }
    return;
  }
  int i = blockIdx.x * 256 + threadIdx.x;
  if (i < 746496) { int n = i / KPG, k = i % KPG;
    wv1b[i] = (n < 860 && k < 860) ? f2bf(Wv1[n * 860 + k]) : (ushort)0; return; }
  i -= 746496;
  if (i < 746496) { int n = i / KPG, k = i % KPG;
    wv2b[i] = (n < 860 && k < 860) ? f2bf(Wv2[n * 860 + k]) : (ushort)0; return; }
  i -= 746496;
  if (i < 153600) { ipwb[i] = f2bf(ipw[i]); return; }
  i -= 153600;
  if (i < 51200)  { owb[i] = f2bf(ow[i]); return; }
  i -= 51200;
  if (i < 40960)  { l1wb[i] = f2bf(l1w[i]); return; }
  i -= 40960;
  if (i < 40960)  { l2wb[i] = f2bf(l2w[i]); return; }
  i -= 40960;
  if (i < 110592) { v2acc[i] = 0.f; return; }
  i -= 110592;
  if (i < 20480)  { int b = i / D_TR, d = i - b * D_TR;   // zero featacc cols < 160
    featacc[b * D_FIN + d] = 0.f; return; }
  i -= 20480;
  if (i < 4608)   { int b = i / DINP, ii = i - b * DINP;  // emb -> featacc cols 160..195
    float s = emb_b[ii];
    #pragma unroll
    for (int k = 0; k < 9; k++) s = fmaf(stat[b * 9 + k], emb_w[ii * 9 + k], s);
    featacc[b * D_FIN + D_TR + ii] = s; return; }
  i -= 4608;
  if (i < 184320) {  // zero obuf16 pad rows t in [215,224)
    int b = i / 1440, rem = i % 1440;
    int t = 215 + rem / 160, cc = rem % 160;
    obuf16[((size_t)b * TP + t) * D_TR + cc] = 0; return;
  }
}

// s1_16[b,n] = bf16( (1/36) sum_i V1b[b*36+i, n] ), stride KPG, zero-pad
__global__ __launch_bounds__(256) void k_red_s1(const ushort* __restrict__ V1b, ushort* __restrict__ s1) {
  int idx = blockIdx.x * 256 + threadIdx.x;
  if (idx >= B_N * KPG) return;
  int b = idx / KPG, n = idx % KPG;
  float s = 0.f;
  if (n < 860) {
    #pragma unroll 4
    for (int i = 0; i < DINP; i++) s += bf2f(V1b[((size_t)b * DINP + i) * 860 + n]);
    s *= (1.0f / 36.0f);
  }
  s1[idx] = (n < 860) ? f2bf(s) : (ushort)0;
}

// x16[b,t,*] (b-major) from relu(v2acc + bv2) and inline pe; pad rows zeroed
__global__ __launch_bounds__(256) void k_buildx(const float* __restrict__ v2acc,
    const float* __restrict__ bv2, const float* __restrict__ times,
    ushort* __restrict__ x16) {
  int idx = blockIdx.x * 256 + threadIdx.x;
  if (idx >= B_N * TP * 40) return;
  int c = idx % 40;
  int r = idx / 40;            // r = b*224 + t
  int t = r % TP, b = r / TP;
  float4 f = {0.f, 0.f, 0.f, 0.f};
  if (t < T_LEN) {
    if (c < 36) {
      float4 a = *(const float4*)&v2acc[(size_t)b * KPG + 4 * t];
      float4 bb = *(const float4*)&bv2[4 * t];
      f.x = fmaxf(a.x + bb.x, 0.f); f.y = fmaxf(a.y + bb.y, 0.f);
      f.z = fmaxf(a.z + bb.z, 0.f); f.w = fmaxf(a.w + bb.w, 0.f);
    } else {
      float tm = times[t * B_N + b];
      int j0 = (c - 36) * 4;
      bool is_sin = j0 < 8;
      int kb = j0 & 7;
      float o[4];
      #pragma unroll
      for (int qq = 0; qq < 4; qq++) {
        float ts = expf((float)(kb + qq) * 0.76723400f);  // 215^(k/7)
        float sc = tm / ts;
        o[qq] = is_sin ? sinf(sc) : cosf(sc);
      }
      f.x = o[0]; f.y = o[1]; f.z = o[2]; f.w = o[3];
    }
  }
  ushort4 h = {f2bf(f.x), f2bf(f.y), f2bf(f.z), f2bf(f.w)};
  *(ushort4*)(x16 + (size_t)r * D_TR + 4 * c) = h;
}

// ---------------- bf16 MFMA GEMM: C = act(A[M,KP] @ W[N,KP]^T + bias), BN templated ----------------
template <int RELU, int SPLIT, int WMODE, int BNT>
__global__ __launch_bounds__(256) void gemm_bf16(const ushort* __restrict__ A,
    const ushort* __restrict__ W, const float* __restrict__ bias, void* __restrict__ Cv,
    int KP, int ldc, int ncols, int kts) {
  __shared__ ushort As[128 * 32];
  __shared__ ushort Ws[BNT * 32];
  constexpr int NJ = BNT / 16;
  const int tid = threadIdx.x;
  const int wave = tid >> 6, lane = tid & 63;
  const int lr = lane & 15, hi = lane >> 4;
  const int m0 = blockIdx.y * 128, n0 = blockIdx.x * BNT;
  const int kt0 = blockIdx.z * kts;

  f32x4 acc[2][NJ];
  #pragma unroll
  for (int i = 0; i < 2; i++)
    #pragma unroll
    for (int j = 0; j < NJ; j++) acc[i][j] = (f32x4){0.f, 0.f, 0.f, 0.f};

  const int ar = tid >> 2, g = tid & 3;
  const size_t abase0 = (size_t)(m0 + ar) * KP;
  const size_t abase1 = (size_t)(m0 + ar + 64) * KP;
  const size_t bbase0 = (size_t)(n0 + ar) * KP;
  const size_t bbase1 = (size_t)(n0 + ar + 64) * KP;
  const int awb0 = ar * 64 + ((g * 16) ^ ((ar & 3) << 4));
  const int awb1 = awb0 + 64 * 64;

  const int arow0 = wave * 32 + lr;
  const int arb0 = arow0 * 64 + ((hi * 16) ^ ((arow0 & 3) << 4));
  const int arb1 = (arow0 + 16) * 64 + ((hi * 16) ^ (((arow0 + 16) & 3) << 4));
  int brb[NJ];
  #pragma unroll
  for (int j = 0; j < NJ; j++)
    brb[j] = (j * 16 + lr) * 64 + ((hi * 16) ^ ((lr & 3) << 4));

  for (int kt = 0; kt < kts; ++kt) {
    const int k0 = (kt0 + kt) * 32;
    uint4 va0 = *(const uint4*)(A + abase0 + k0 + g * 8);
    uint4 va1 = *(const uint4*)(A + abase1 + k0 + g * 8);
    uint4 vb0 = *(const uint4*)(W + bbase0 + k0 + g * 8);
    uint4 vb1;
    if constexpr (BNT == 128) vb1 = *(const uint4*)(W + bbase1 + k0 + g * 8);
    if (kt) __syncthreads();
    *(uint4*)((char*)As + awb0) = va0;
    *(uint4*)((char*)As + awb1) = va1;
    *(uint4*)((char*)Ws + awb0) = vb0;
    if constexpr (BNT == 128) *(uint4*)((char*)Ws + awb1) = vb1;
    __syncthreads();
    short8v a0 = *(const short8v*)((const char*)As + arb0);
    short8v a1 = *(const short8v*)((const char*)As + arb1);
    #pragma unroll
    for (int j = 0; j < NJ; j++) {
      short8v bf = *(const short8v*)((const char*)Ws + brb[j]);
      acc[0][j] = __builtin_amdgcn_mfma_f32_16x16x32_bf16(a0, bf, acc[0][j], 0, 0, 0);
      acc[1][j] = __builtin_amdgcn_mfma_f32_16x16x32_bf16(a1, bf, acc[1][j], 0, 0, 0);
    }
  }

  #pragma unroll
  for (int i = 0; i < 2; i++) {
    #pragma unroll
    for (int j = 0; j < NJ; j++) {
      int col = n0 + j * 16 + lr;
      int row = m0 + wave * 32 + i * 16 + hi * 4;
      if (col < ncols) {
        if constexpr (SPLIT) {
          #pragma unroll
          for (int r = 0; r < 4; r++)
            atomicAdd((float*)Cv + (size_t)(row + r) * ldc + col, acc[i][j][r]);
        } else {
          float bb = bias ? bias[col] : 0.f;
          #pragma unroll
          for (int r = 0; r < 4; r++) {
            float xv = acc[i][j][r] + bb;
            if (RELU) xv = fmaxf(xv, 0.f);
            if (WMODE == 0) ((float*)Cv)[(size_t)(row + r) * ldc + col] = xv;
            else            ((ushort*)Cv)[(size_t)(row + r) * ldc + col] = f2bf(xv);
          }
        }
      }
    }
  }
}

// ---------------- qkv GEMM (BN=160, per-role blocks): role 0=Q, 1=K (row-major), 2=V (-> Vt) ----------------
__global__ __launch_bounds__(256) void gemm_qkv(const ushort* __restrict__ A,
    const ushort* __restrict__ W, const float* __restrict__ bias,
    ushort* __restrict__ qkvB, ushort* __restrict__ Vt, int kts) {
  __shared__ ushort As[128 * 32];
  __shared__ ushort Ws[160 * 32];
  const int KP = 160;
  const int tid = threadIdx.x;
  const int wave = tid >> 6, lane = tid & 63;
  const int lr = lane & 15, hi = lane >> 4;
  const int m0 = blockIdx.y * 128;
  const int role = blockIdx.x;            // 0=Q, 1=K, 2=V
  const int n0 = role * 160;

  f32x4 acc[2][10];
  #pragma unroll
  for (int i = 0; i < 2; i++)
    #pragma unroll
    for (int j = 0; j < 10; j++) acc[i][j] = (f32x4){0.f, 0.f, 0.f, 0.f};

  const int ar = tid >> 2, g = tid & 3;
  const size_t abase0 = (size_t)(m0 + ar) * KP;
  const size_t abase1 = (size_t)(m0 + ar + 64) * KP;
  const int awb0 = ar * 64 + ((g * 16) ^ ((ar & 3) << 4));
  const int awb1 = awb0 + 64 * 64;
  // W staging: 160 rows x 2 granules = 640 granules over 256 threads (3-part, gemm_ln pattern)
  const int wr0 = tid >> 2,         ws0 = tid & 3;
  const int wr1 = (tid + 256) >> 2, ws1 = (tid + 256) & 3;
  const int wr2 = (tid + 512) >> 2, ws2 = (tid + 512) & 3;
  const int wwb0 = wr0 * 64 + ((ws0 * 16) ^ ((wr0 & 3) << 4));
  const int wwb1 = wr1 * 64 + ((ws1 * 16) ^ ((wr1 & 3) << 4));
  const int wwb2 = wr2 * 64 + ((ws2 * 16) ^ ((wr2 & 3) << 4));

  const int arow0 = wave * 32 + lr;
  const int arb0 = arow0 * 64 + ((hi * 16) ^ ((arow0 & 3) << 4));
  const int arb1 = (arow0 + 16) * 64 + ((hi * 16) ^ (((arow0 + 16) & 3) << 4));
  int brb[10];
  #pragma unroll
  for (int j = 0; j < 10; j++)
    brb[j] = (j * 16 + lr) * 64 + ((hi * 16) ^ ((lr & 3) << 4));

  for (int kt = 0; kt < kts; ++kt) {
    const int k0 = kt * 32;
    uint4 va0 = *(const uint4*)(A + abase0 + k0 + g * 8);
    uint4 va1 = *(const uint4*)(A + abase1 + k0 + g * 8);
    uint4 w0 = *(const uint4*)(W + (size_t)(n0 + wr0) * KP + k0 + ws0 * 8);
    uint4 w1 = *(const uint4*)(W + (size_t)(n0 + wr1) * KP + k0 + ws1 * 8);
    uint4 w2;
    if (tid < 128) w2 = *(const uint4*)(W + (size_t)(n0 + wr2) * KP + k0 + ws2 * 8);
    if (kt) __syncthreads();
    *(uint4*)((char*)As + awb0) = va0;
    *(uint4*)((char*)As + awb1) = va1;
    *(uint4*)((char*)Ws + wwb0) = w0;
    *(uint4*)((char*)Ws + wwb1) = w1;
    if (tid < 128) *(uint4*)((char*)Ws + wwb2) = w2;
    __syncthreads();
    short8v a0 = *(const short8v*)((const char*)As + arb0);
    short8v a1 = *(const short8v*)((const char*)As + arb1);
    #pragma unroll
    for (int j = 0; j < 10; j++) {
      short8v bf = *(const short8v*)((const char*)Ws + brb[j]);
      acc[0][j] = __builtin_amdgcn_mfma_f32_16x16x32_bf16(a0, bf, acc[0][j], 0, 0, 0);
      acc[1][j] = __builtin_amdgcn_mfma_f32_16x16x32_bf16(a1, bf, acc[1][j], 0, 0, 0);
    }
  }

  #pragma unroll
  for (int i = 0; i < 2; i++) {
    const int row = m0 + wave * 32 + i * 16 + hi * 4;   // = b*224 + t0 (4 consecutive t)
    const int b = row / TP, t0 = row - b * TP;
    #pragma unroll
    for (int j = 0; j < 10; j++) {
      const int cl = j * 16 + lr;           // local col 0..159
      const float bb = bias[n0 + cl];
      if (role < 2) {                       // Q or K: row-major scalar stores
        #pragma unroll
        for (int r = 0; r < 4; r++)
          qkvB[(size_t)(row + r) * 480 + n0 + cl] = f2bf(acc[i][j][r] + bb);
      } else {                              // V: transposed packed store (4 consecutive t = 8B)
        int hh = cl / 40, dd = cl - hh * 40;
        ushort4 pv;
        pv.x = f2bf(acc[i][j][0] + bb); pv.y = f2bf(acc[i][j][1] + bb);
        pv.z = f2bf(acc[i][j][2] + bb); pv.w = f2bf(acc[i][j][3] + bb);
        *(ushort4*)(Vt + (((size_t)(b * 4 + hh) * 48 + dd) * TP + t0)) = pv;
      }
    }
  }
}

// ---------------- fused layer tail: [attn-out GEMM + res + LN1] -> [FF1] -> [FF2 + res + LN2] ----------------
__global__ __launch_bounds__(256) void gemm_lnff(const ushort* __restrict__ Ao,
    const ushort* __restrict__ Wo, const float* __restrict__ bo,
    const float* __restrict__ g1, const float* __restrict__ be1,
    const ushort* __restrict__ W1, const float* __restrict__ b1,
    const ushort* __restrict__ W2, const float* __restrict__ b2,
    const float* __restrict__ g2, const float* __restrict__ be2,
    ushort* __restrict__ x16, const int* __restrict__ lengths,
    float* __restrict__ featacc) {
  __shared__ ushort As[64 * 32];
  __shared__ ushort Ws[160 * 32];
  __shared__ ushort W1s[128 * 32];
  __shared__ ushort W2s[160 * 32];
  __shared__ ushort Xln[64 * 168];
  __shared__ ushort Hs[64 * 136];
  const int tid = threadIdx.x;
  const int wave = tid >> 6, lane = tid & 63;
  const int lr = lane & 15, hi = lane >> 4;
  const int m0 = blockIdx.x * 64;

  const int ar = tid >> 2, g = tid & 3;
  const int awb = ar * 64 + ((g * 16) ^ ((ar & 3) << 4));
  const int awb1 = awb + 64 * 64;
  const int wr0 = tid >> 2,         ws0 = tid & 3;
  const int wr1 = (tid + 256) >> 2, ws1 = (tid + 256) & 3;
  const int wr2 = (tid + 512) >> 2, ws2 = (tid + 512) & 3;
  const int wwb0 = wr0 * 64 + ((ws0 * 16) ^ ((wr0 & 3) << 4));
  const int wwb1 = wr1 * 64 + ((ws1 * 16) ^ ((wr1 & 3) << 4));
  const int wwb2 = wr2 * 64 + ((ws2 * 16) ^ ((wr2 & 3) << 4));
  const int arow = wave * 16 + lr;
  const int arb = arow * 64 + ((hi * 16) ^ ((arow & 3) << 4));
  int brb[10];
  #pragma unroll
  for (int j = 0; j < 10; j++)
    brb[j] = (j * 16 + lr) * 64 + ((hi * 16) ^ ((lr & 3) << 4));

  const int lrow0 = wave * 16 + hi * 4;
  const int rb = m0 + lrow0;

  // ======== phase A: attn-out GEMM (K=160) + bias + residual + LN1 -> Xln ========
  {
    f32x4 acc[10];
    #pragma unroll
    for (int j = 0; j < 10; j++) acc[j] = (f32x4){0.f, 0.f, 0.f, 0.f};
    const size_t abase = (size_t)(m0 + ar) * 160;
    for (int kt = 0; kt < 5; ++kt) {
      const int k0 = kt * 32;
      uint4 va = *(const uint4*)(Ao + abase + k0 + g * 8);
      uint4 w0 = *(const uint4*)(Wo + (size_t)wr0 * 160 + k0 + ws0 * 8);
      uint4 w1 = *(const uint4*)(Wo + (size_t)wr1 * 160 + k0 + ws1 * 8);
      uint4 w2;
      if (tid < 128) w2 = *(const uint4*)(Wo + (size_t)wr2 * 160 + k0 + ws2 * 8);
      if (kt) __syncthreads();
      *(uint4*)((char*)As + awb) = va;
      *(uint4*)((char*)Ws + wwb0) = w0;
      *(uint4*)((char*)Ws + wwb1) = w1;
      if (tid < 128) *(uint4*)((char*)Ws + wwb2) = w2;
      __syncthreads();
      short8v a0 = *(const short8v*)((const char*)As + arb);
      #pragma unroll
      for (int j = 0; j < 10; j++) {
        short8v bf = *(const short8v*)((const char*)Ws + brb[j]);
        acc[j] = __builtin_amdgcn_mfma_f32_16x16x32_bf16(a0, bf, acc[j], 0, 0, 0);
      }
    }
    float s[4] = {0.f, 0.f, 0.f, 0.f};
    #pragma unroll
    for (int j = 0; j < 10; j++) {
      const int col = j * 16 + lr;
      const float bb = bo[col];
      #pragma unroll
      for (int r = 0; r < 4; r++) {
        float v = acc[j][r] + bb + bf2f(x16[(size_t)(rb + r) * D_TR + col]);
        acc[j][r] = v;
        s[r] += v;
      }
    }
    #pragma unroll
    for (int r = 0; r < 4; r++) {
      s[r] += __shfl_xor(s[r], 1, 64);
      s[r] += __shfl_xor(s[r], 2, 64);
      s[r] += __shfl_xor(s[r], 4, 64);
      s[r] += __shfl_xor(s[r], 8, 64);
    }
    float mu[4], q2[4] = {0.f, 0.f, 0.f, 0.f};
    #pragma unroll
    for (int r = 0; r < 4; r++) mu[r] = s[r] * (1.0f / 160.0f);
    #pragma unroll
    for (int j = 0; j < 10; j++)
      #pragma unroll
      for (int r = 0; r < 4; r++) {
        float d = acc[j][r] - mu[r];
        q2[r] += d * d;
      }
    #pragma unroll
    for (int r = 0; r < 4; r++) {
      q2[r] += __shfl_xor(q2[r], 1, 64);
      q2[r] += __shfl_xor(q2[r], 2, 64);
      q2[r] += __shfl_xor(q2[r], 4, 64);
      q2[r] += __shfl_xor(q2[r], 8, 64);
    }
    float rstd[4];
    #pragma unroll
    for (int r = 0; r < 4; r++) rstd[r] = rsqrtf(q2[r] * (1.0f / 160.0f) + 1e-5f);
    #pragma unroll
    for (int j = 0; j < 10; j++) {
      const int col = j * 16 + lr;
      const float gc = g1[col], bc = be1[col];
      #pragma unroll
      for (int r = 0; r < 4; r++) {
        float o = (acc[j][r] - mu[r]) * rstd[r] * gc + bc;
        Xln[(lrow0 + r) * 168 + col] = f2bf(o);
      }
    }
  }
  __syncthreads();

  // ======== phase B: h = relu(Xln @ W1^T + b1) -> Hs ========
  {
    f32x4 acc1[8];
    #pragma unroll
    for (int j = 0; j < 8; j++) acc1[j] = (f32x4){0.f, 0.f, 0.f, 0.f};
    int brb8[8];
    #pragma unroll
    for (int j = 0; j < 8; j++)
      brb8[j] = (j * 16 + lr) * 64 + ((hi * 16) ^ ((lr & 3) << 4));
    for (int kt = 0; kt < 5; ++kt) {
      const int k0 = kt * 32;
      uint4 w10 = *(const uint4*)(W1 + (size_t)ar * 160 + k0 + g * 8);
      uint4 w11 = *(const uint4*)(W1 + (size_t)(ar + 64) * 160 + k0 + g * 8);
      if (kt) __syncthreads();
      *(uint4*)((char*)W1s + awb) = w10;
      *(uint4*)((char*)W1s + awb1) = w11;
      __syncthreads();
      short8v a0 = *(const short8v*)(&Xln[(wave * 16 + lr) * 168 + k0 + hi * 8]);
      #pragma unroll
      for (int j = 0; j < 8; j++) {
        short8v bf = *(const short8v*)((const char*)W1s + brb8[j]);
        acc1[j] = __builtin_amdgcn_mfma_f32_16x16x32_bf16(a0, bf, acc1[j], 0, 0, 0);
      }
    }
    #pragma unroll
    for (int j = 0; j < 8; j++) {
      const int col = j * 16 + lr;
      const float bb = b1[col];
      #pragma unroll
      for (int r = 0; r < 4; r++)
        Hs[(lrow0 + r) * 136 + col] = f2bf(fmaxf(acc1[j][r] + bb, 0.f));
    }
  }
  __syncthreads();

  // ======== phase C: o = Hs @ W2^T + b2; + Xln residual + LN2 -> x16 / featacc ========
  {
    f32x4 acc[10];
    #pragma unroll
    for (int j = 0; j < 10; j++) acc[j] = (f32x4){0.f, 0.f, 0.f, 0.f};
    for (int kt = 0; kt < 4; ++kt) {
      const int k0 = kt * 32;
      uint4 w0 = *(const uint4*)(W2 + (size_t)wr0 * 128 + k0 + ws0 * 8);
      uint4 w1 = *(const uint4*)(W2 + (size_t)wr1 * 128 + k0 + ws1 * 8);
      uint4 w2;
      if (tid < 128) w2 = *(const uint4*)(W2 + (size_t)wr2 * 128 + k0 + ws2 * 8);
      if (kt) __syncthreads();
      *(uint4*)((char*)W2s + wwb0) = w0;
      *(uint4*)((char*)W2s + wwb1) = w1;
      if (tid < 128) *(uint4*)((char*)W2s + wwb2) = w2;
      __syncthreads();
      short8v a0 = *(const short8v*)(&Hs[(wave * 16 + lr) * 136 + k0 + hi * 8]);
      #pragma unroll
      for (int j = 0; j < 10; j++) {
        short8v bf = *(const short8v*)((const char*)W2s + brb[j]);
        acc[j] = __builtin_amdgcn_mfma_f32_16x16x32_bf16(a0, bf, acc[j], 0, 0, 0);
      }
    }
    float s[4] = {0.f, 0.f, 0.f, 0.f};
    #pragma unroll
    for (int j = 0; j < 10; j++) {
      const int col = j * 16 + lr;
      const float bb = b2[col];
      #pragma unroll
      for (int r = 0; r < 4; r++) {
        float v = acc[j][r] + bb + bf2f(Xln[(lrow0 + r) * 168 + col]);
        acc[j][r] = v;
        s[r] += v;
      }
    }
    #pragma unroll
    for (int r = 0; r < 4; r++) {
      s[r] += __shfl_xor(s[r], 1, 64);
      s[r] += __shfl_xor(s[r], 2, 64);
      s[r] += __shfl_xor(s[r], 4, 64);
      s[r] += __shfl_xor(s[r], 8, 64);
    }
    float mu[4], q2[4] = {0.f, 0.f, 0.f, 0.f};
    #pragma unroll
    for (int r = 0; r < 4; r++) mu[r] = s[r] * (1.0f / 160.0f);
    #pragma unroll
    for (int j = 0; j < 10; j++)
      #pragma unroll
      for (int r = 0; r < 4; r++) {
        float d = acc[j][r] - mu[r];
        q2[r] += d * d;
      }
    #pragma unroll
    for (int r = 0; r < 4; r++) {
      q2[r] += __shfl_xor(q2[r], 1, 64);
      q2[r] += __shfl_xor(q2[r], 2, 64);
      q2[r] += __shfl_xor(q2[r], 4, 64);
      q2[r] += __shfl_xor(q2[r], 8, 64);
    }
    float rstd[4];
    #pragma unroll
    for (int r = 0; r < 4; r++) rstd[r] = rsqrtf(q2[r] * (1.0f / 160.0f) + 1e-5f);

    if (featacc == nullptr) {
      #pragma unroll
      for (int j = 0; j < 10; j++) {
        const int col = j * 16 + lr;
        const float gc = g2[col], bc = be2[col];
        #pragma unroll
        for (int r = 0; r < 4; r++) {
          float o = (acc[j][r] - mu[r]) * rstd[r] * gc + bc;
          x16[(size_t)(rb + r) * D_TR + col] = f2bf(o);
        }
      }
    } else {
      const int b = rb / TP, t0 = rb - b * TP;
      int L = lengths[b]; if (L > T_LEN) L = T_LEN;
      #pragma unroll
      for (int j = 0; j < 10; j++) {
        const int col = j * 16 + lr;
        const float gc = g2[col], bc = be2[col];
        float sacc = 0.f;
        #pragma unroll
        for (int r = 0; r < 4; r++) {
          float o = (acc[j][r] - mu[r]) * rstd[r] * gc + bc;
          if (t0 + r < L) sacc += o;
        }
        if (t0 < L) atomicAdd(&featacc[b * D_FIN + col], sacc);
      }
    }
  }
}

// ---------------- barrier-free 1-wave flash attention (b-major qkv + Vt) ----------------
__global__ __launch_bounds__(64) void k_attn4(const ushort* __restrict__ qkvB,
    const ushort* __restrict__ Vt, const int* __restrict__ lengths,
    ushort* __restrict__ o16) {
  __shared__ ushort SP[16 * 232];
  const int bh = blockIdx.x;
  const int b = bh >> 2, h = bh & 3;
  int L = lengths[b]; if (L > T_LEN) L = T_LEN;
  const int q0 = blockIdx.y << 4;
  if (q0 >= L) return;
  const int lane = threadIdx.x;
  const int lr = lane & 15, hi = lane >> 4;
  const int nk16 = (L + 15) >> 4;
  const int nkt  = (L + 31) >> 5;
  const float SC = 0.15811388300841898f;  // 1/sqrt(40)

  const ushort* qrow = qkvB + ((size_t)b * TP + q0) * 480 + h * 40;
  uint4 qa0u = *(const uint4*)(qrow + lr * 480 + hi * 8);
  uint4 qa1u = {0, 0, 0, 0};
  if (hi == 0) qa1u = *(const uint4*)(qrow + lr * 480 + 32);
  short8v qa0 = *(short8v*)&qa0u;
  short8v qa1 = *(short8v*)&qa1u;

  f32x4 c[14];
  #pragma unroll
  for (int kt = 0; kt < 14; ++kt) {
    c[kt] = (f32x4){0.f, 0.f, 0.f, 0.f};
    if (kt < nk16) {
      const ushort* krow = qkvB + ((size_t)b * TP + kt * 16) * 480 + 160 + h * 40;
      uint4 kb0u = *(const uint4*)(krow + lr * 480 + hi * 8);
      uint4 kb1u = {0, 0, 0, 0};
      if (hi == 0) kb1u = *(const uint4*)(krow + lr * 480 + 32);
      c[kt] = __builtin_amdgcn_mfma_f32_16x16x32_bf16(qa0, *(short8v*)&kb0u, c[kt], 0, 0, 0);
      c[kt] = __builtin_amdgcn_mfma_f32_16x16x32_bf16(qa1, *(short8v*)&kb1u, c[kt], 0, 0, 0);
    }
  }

  float mx[4] = {-1e30f, -1e30f, -1e30f, -1e30f};
  #pragma unroll
  for (int kt = 0; kt < 14; ++kt) {
    if (kt < nk16) {
      bool valid = (kt * 16 + lr) < L;
      #pragma unroll
      for (int r = 0; r < 4; r++) {
        float v = valid ? c[kt][r] : -1e30f;
        mx[r] = fmaxf(mx[r], v);
      }
    }
  }
  #pragma unroll
  for (int r = 0; r < 4; r++) {
    mx[r] = fmaxf(mx[r], __shfl_xor(mx[r], 1, 64));
    mx[r] = fmaxf(mx[r], __shfl_xor(mx[r], 2, 64));
    mx[r] = fmaxf(mx[r], __shfl_xor(mx[r], 4, 64));
    mx[r] = fmaxf(mx[r], __shfl_xor(mx[r], 8, 64));
  }
  float sum[4] = {0.f, 0.f, 0.f, 0.f};
  #pragma unroll
  for (int kt = 0; kt < 14; ++kt) {
    if (kt < nk16) {
      bool valid = (kt * 16 + lr) < L;
      #pragma unroll
      for (int r = 0; r < 4; r++) {
        float p = valid ? __expf(SC * (c[kt][r] - mx[r])) : 0.f;
        sum[r] += p;
        c[kt][r] = p;
      }
    }
  }
  #pragma unroll
  for (int r = 0; r < 4; r++) {
    sum[r] += __shfl_xor(sum[r], 1, 64);
    sum[r] += __shfl_xor(sum[r], 2, 64);
    sum[r] += __shfl_xor(sum[r], 4, 64);
    sum[r] += __shfl_xor(sum[r], 8, 64);
  }

  const int nk16w = nkt * 2;
  #pragma unroll
  for (int kt = 0; kt < 14; ++kt) {
    if (kt < nk16w) {
      #pragma unroll
      for (int r = 0; r < 4; r++)
        SP[(hi * 4 + r) * 232 + kt * 16 + lr] = f2bf(c[kt][r]);
    }
  }
  __syncthreads();

  f32x4 o0 = {0.f, 0.f, 0.f, 0.f}, o1 = o0, o2 = o0;
  const ushort* vbase = Vt + (size_t)bh * 48 * TP;
  #pragma unroll
  for (int kt = 0; kt < 7; ++kt) {
    if (kt < nkt) {
      short8v pa = *(const short8v*)((const char*)SP + lr * 464 + kt * 64 + hi * 16);
      const ushort* vb = vbase + kt * 32 + hi * 8;
      short8v v0 = *(const short8v*)(vb + (size_t)lr * TP);
      short8v v1 = *(const short8v*)(vb + (size_t)(16 + lr) * TP);
      short8v v2 = *(const short8v*)(vb + (size_t)(32 + lr) * TP);
      o0 = __builtin_amdgcn_mfma_f32_16x16x32_bf16(pa, v0, o0, 0, 0, 0);
      o1 = __builtin_amdgcn_mfma_f32_16x16x32_bf16(pa, v1, o1, 0, 0, 0);
      o2 = __builtin_amdgcn_mfma_f32_16x16x32_bf16(pa, v2, o2, 0, 0, 0);
    }
  }

  #pragma unroll
  for (int r = 0; r < 4; r++) {
    int t = q0 + hi * 4 + r;
    if (t < T_LEN) {
      float inv = 1.0f / sum[r];
      ushort* op = o16 + ((size_t)b * TP + t) * D_TR + h * 40;
      op[lr]      = f2bf(o0[r] * inv);
      op[16 + lr] = f2bf(o1[r] * inv);
      if (lr < 8) op[32 + lr] = f2bf(o2[r] * inv);
    }
  }
}

// ---------------- head: (feat scale) -> mlp1 -> logits, one block per b ----------------
__global__ __launch_bounds__(256) void k_head2(const float* __restrict__ featacc,
    const int* __restrict__ lengths, const float* __restrict__ m1w,
    const float* __restrict__ m1b, const float* __restrict__ m2w,
    const float* __restrict__ m2b, float* __restrict__ out) {
  __shared__ float feat[196];
  __shared__ float m1o_s[196];
  __shared__ float r0[4], r1[4];
  const int b = blockIdx.x, tid = threadIdx.x;
  int L = lengths[b]; if (L > T_LEN) L = T_LEN;
  const float inv = 1.0f / (float)(L + 1);
  if (tid < D_FIN)
    feat[tid] = featacc[(size_t)b * D_FIN + tid] * (tid < D_TR ? inv : 1.f);
  __syncthreads();
  if (tid < D_FIN) {
    float s = m1b[tid];
    const float* wr = m1w + (size_t)tid * D_FIN;
    #pragma unroll 4
    for (int k = 0; k < D_FIN; k++) s = fmaf(feat[k], wr[k], s);
    m1o_s[tid] = fmaxf(s, 0.f);
  }
  __syncthreads();
  float p0 = 0.f, p1 = 0.f;
  if (tid < D_FIN) {
    p0 = m1o_s[tid] * m2w[tid];
    p1 = m1o_s[tid] * m2w[D_FIN + tid];
  }
  #pragma unroll
  for (int off = 32; off; off >>= 1) {
    p0 += __shfl_xor(p0, off, 64);
    p1 += __shfl_xor(p1, off, 64);
  }
  int w = tid >> 6;
  if ((tid & 63) == 0) { r0[w] = p0; r1[w] = p1; }
  __syncthreads();
  if (tid == 0) out[2 * b]     = r0[0] + r0[1] + r0[2] + r0[3] + m2b[0];
  if (tid == 1) out[2 * b + 1] = r1[0] + r1[1] + r1[2] + r1[3] + m2b[1];
  if (b == 0 && tid == 2) out[256] = 0.f;  // distance == 0 exactly
}

// ---------------- launch ----------------
extern "C" void kernel_launch(void* const* d_in, const int* in_sizes, int n_in,
                              void* d_out, int out_size, void* d_ws, size_t ws_size,
                              hipStream_t stream) {
  const float* src   = (const float*)d_in[0];
  const float* stat  = (const float*)d_in[1];
  const float* times = (const float*)d_in[2];
  const int*   lens  = (const int*)d_in[3];
  const float* R_u   = (const float*)d_in[4];
  const float* emb_w = (const float*)d_in[5];
  const float* emb_b = (const float*)d_in[6];
  const float* Wv1   = (const float*)d_in[7];
  const float* bv1   = (const float*)d_in[8];
  const float* Wv2   = (const float*)d_in[9];
  const float* bv2   = (const float*)d_in[10];
  const float* ipw   = (const float*)d_in[11];
  const float* ipb   = (const float*)d_in[12];
  const float* ow    = (const float*)d_in[13];
  const float* ob    = (const float*)d_in[14];
  const float* l1w   = (const float*)d_in[15];
  const float* l1b   = (const float*)d_in[16];
  const float* l2w   = (const float*)d_in[17];
  const float* l2b   = (const float*)d_in[18];
  const float* ln1s  = (const float*)d_in[19];
  const float* ln1bb = (const float*)d_in[20];
  const float* ln2s  = (const float*)d_in[21];
  const float* ln2bb = (const float*)d_in[22];
  const float* m1w   = (const float*)d_in[23];
  const float* m1b   = (const float*)d_in[24];
  const float* m2w   = (const float*)d_in[25];
  const float* m2b   = (const float*)d_in[26];
  float* out = (float*)d_out;

  // ---- workspace layout (bytes) ----
  char* p = (char*)d_ws;
  ushort* x16    = (ushort*)p;  p += 9175040;   // 28672 x 160 bf16 (b-major)
  float*  v2acc  = (float*)p;   p += 442368;    // 128 x 864 fp32
  ushort* s1b    = (ushort*)p;  p += 221184;    // 128 x 864 bf16
  ushort* obuf16 = (ushort*)p;  p += 9175040;   // 28672 x 160 bf16 (b-major)
  ushort* wv1b   = (ushort*)p;  p += 1492992;   // 864 x 864 bf16
  ushort* wv2b   = (ushort*)p;  p += 1492992;
  ushort* ipwb   = (ushort*)p;  p += 307200;    // 2 x 480 x 160
  ushort* owb    = (ushort*)p;  p += 102400;    // 2 x 160 x 160
  ushort* l1wb   = (ushort*)p;  p += 81920;     // 2 x 128 x 160
  ushort* l2wb   = (ushort*)p;  p += 81920;     // 2 x 160 x 128
  float*  featacc= (float*)p;   p += 100352;    // 128 x 196 fp32
  char*   R2     = p;
  ushort* xb16   = (ushort*)R2;                  // phase A: 4608 x 864 bf16 (7.96 MB)
  ushort* V1b    = (ushort*)(R2 + 7962624);      // phase A: 4608 x 860 bf16 (7.93 MB)
  ushort* qkvB   = (ushort*)R2;                  // phase B: 128 x 224 x 480 bf16 (27.5 MB)
  ushort* Vt     = (ushort*)(R2 + 27525120);     // 512 x 48 x 224 bf16 (11 MB)

  k_prep<<<8330, 256, 0, stream>>>(Wv1, Wv2, ipw, ow, l1w, l2w, src, R_u,
                                   stat, emb_w, emb_b,
                                   wv1b, wv2b, ipwb, owb, l1wb, l2wb,
                                   v2acc, featacc, obuf16, xb16);

  // V1b = bf16(relu(xb @ Wv1^T + bv1)), BN=64 -> 504 blocks (2 blocks/CU)
  gemm_bf16<1, 0, 1, 64><<<dim3(14, 36, 1), 256, 0, stream>>>(
      xb16, wv1b, bv1, V1b, KPG, 860, 860, 27);
  k_red_s1<<<432, 256, 0, stream>>>(V1b, s1b);
  gemm_bf16<0, 1, 0, 64><<<dim3(14, 1, 9), 256, 0, stream>>>(
      s1b, wv2b, nullptr, v2acc, KPG, KPG, KPG, 3);
  k_buildx<<<4480, 256, 0, stream>>>(v2acc, bv2, times, x16);

  for (int l = 0; l < 2; l++) {
    gemm_qkv<<<dim3(3, 224, 1), 256, 0, stream>>>(
        x16, ipwb + (size_t)l * 76800, ipb + l * 480, qkvB, Vt, 5);
    k_attn4<<<dim3(512, 14), 64, 0, stream>>>(qkvB, Vt, lens, obuf16);
    gemm_lnff<<<448, 256, 0, stream>>>(
        obuf16, owb + (size_t)l * 25600, ob + l * 160,
        ln1s + l * 160, ln1bb + l * 160,
        l1wb + (size_t)l * 20480, l1b + l * 128,
        l2wb + (size_t)l * 20480, l2b + l * 160,
        ln2s + l * 160, ln2bb + l * 160,
        x16, lens, (l == 1) ? featacc : nullptr);
  }

  k_head2<<<128, 256, 0, stream>>>(featacc, lens, m1w, m1b, m2w, m2b, out);
}